// Round 13
// baseline (162.601 us; speedup 1.0000x reference)
//
#include <hip/hip_runtime.h>
#include <hip/hip_bf16.h>

typedef __bf16 bf16x8 __attribute__((ext_vector_type(8)));
typedef __bf16 bf16x4 __attribute__((ext_vector_type(4)));
typedef float f32x4 __attribute__((ext_vector_type(4)));

#define H1 512
#define H 2048
#define OUTN 1024
#define T 4096

// ---------------------------------------------------------------------------
// Generic row-wise matvec: out[r] = act(dot(W[r,:], x) + b[r])
// ---------------------------------------------------------------------------
__global__ __launch_bounds__(256) void matvec_k(
    const float* __restrict__ W, const float* __restrict__ x,
    const float* __restrict__ b, float* __restrict__ out,
    int R, int K, int relu)
{
    int row = blockIdx.x * 4 + (threadIdx.x >> 6);
    int lane = threadIdx.x & 63;
    if (row >= R) return;
    const float* Wr = W + (size_t)row * K;
    float s = 0.f;
    for (int k = lane * 4; k < K; k += 256) {
        float4 w4 = *(const float4*)(Wr + k);
        float4 x4 = *(const float4*)(x + k);
        s += w4.x * x4.x + w4.y * x4.y + w4.z * x4.z + w4.w * x4.w;
    }
    #pragma unroll
    for (int m = 32; m; m >>= 1) s += __shfl_xor(s, m, 64);
    if (lane == 0) {
        if (b) s += b[row];
        if (relu) s = fmaxf(s, 0.f);
        out[row] = s;
    }
}

// ---------------------------------------------------------------------------
// Wide matvec for the big GRU weights: 32 B/lane/iter (2 x float4), two
// independent accumulators -> 2x memory-level parallelism per wave.
// ---------------------------------------------------------------------------
__global__ __launch_bounds__(256) void matvec_wide_k(
    const float* __restrict__ W, const float* __restrict__ x,
    const float* __restrict__ b, float* __restrict__ out,
    int R, int K)
{
    int row = blockIdx.x * 4 + (threadIdx.x >> 6);
    int lane = threadIdx.x & 63;
    if (row >= R) return;
    const float* Wr = W + (size_t)row * K;
    float s0 = 0.f, s1 = 0.f;
    for (int k = lane * 8; k < K; k += 512) {
        float4 w0 = *(const float4*)(Wr + k);
        float4 w1 = *(const float4*)(Wr + k + 4);
        float4 x0 = *(const float4*)(x + k);
        float4 x1 = *(const float4*)(x + k + 4);
        s0 += w0.x * x0.x + w0.y * x0.y + w0.z * x0.z + w0.w * x0.w;
        s1 += w1.x * x1.x + w1.y * x1.y + w1.z * x1.z + w1.w * x1.w;
    }
    float s = s0 + s1;
    #pragma unroll
    for (int m = 32; m; m >>= 1) s += __shfl_xor(s, m, 64);
    if (lane == 0) {
        if (b) s += b[row];
        out[row] = s;
    }
}

// ---------------------------------------------------------------------------
// One-shot fp32 -> bf16 convert (proven r7-r12).
// E: FRAGMENT-MAJOR Efrag[r16][k32][lane][8] (MFMA A-operand lane order).
// attn2_w: XOR-swizzled rows (chunk cc -> slot cc^(row&7) per 64-col group).
// Block 0 additionally zeroes the attn_applied accumulator (8 KB).
// ---------------------------------------------------------------------------
__global__ __launch_bounds__(256) void cvt_frag_k(
    const float* __restrict__ E, const float* __restrict__ W2,
    __bf16* __restrict__ dst, float* __restrict__ zero_acc)
{
    if (blockIdx.x == 0) {
        #pragma unroll
        for (int j = 0; j < 8; ++j)
            zero_acc[threadIdx.x + 256 * j] = 0.f;
    }
    const int EC = T * H / 8;
    int c = blockIdx.x * 256 + threadIdx.x;
    const float* src;
    __bf16* d;
    if (c < EC) {
        int lane = c & 63;
        int k32 = (c >> 6) & 63;
        int r16 = c >> 12;
        int row = r16 * 16 + (lane & 15);
        int col = k32 * 32 + (lane >> 4) * 8;
        src = E + (size_t)row * H + col;
        d = dst + (size_t)c * 8;
    } else {
        int c2 = c - EC;
        int row = c2 >> 8;
        int kc = c2 & 255;
        src = W2 + (size_t)row * H + kc * 8;
        int grp = kc >> 3, cc = kc & 7;
        int sw = cc ^ (row & 7);
        d = dst + (size_t)T * H + (size_t)row * H + grp * 64 + sw * 8;
    }
    float4 a = *(const float4*)src;
    float4 b = *(const float4*)(src + 4);
    bf16x8 v = {(__bf16)a.x, (__bf16)a.y, (__bf16)a.z, (__bf16)a.w,
                (__bf16)b.x, (__bf16)b.y, (__bf16)b.z, (__bf16)b.w};
    *(bf16x8*)d = v;
}

// ---------------------------------------------------------------------------
// gamma GEMM v11 (proven r11/r12; 64x64 tile, 4 waves pure-m, 2048 blocks =
// 8/CU full occupancy, frag-major A direct to VGPR, swizzled B-LDS,
// partial-write epilogue). Writes gpart[hb][t].
// ---------------------------------------------------------------------------
__global__ __launch_bounds__(256, 8) void gamma_gemm11(
    const __bf16* __restrict__ Efrag,  // [T/16][64][64][8] fragment-major
    const __bf16* __restrict__ Bsw,    // [H][2048] swizzled bf16
    const float* __restrict__ way, const float* __restrict__ a3,
    float* __restrict__ gpart)         // [H/64][T]
{
    __shared__ __attribute__((aligned(16))) __bf16 Bs[64][64];   // 8 KB
    __shared__ float wayS[64], a3S[64];

    const int tb = blockIdx.x, hb = blockIdx.y;
    const int tid = threadIdx.x, lane = tid & 63, wid = tid >> 6;
    if (tid < 64) { wayS[tid] = way[hb * 64 + tid]; a3S[tid] = a3[hb * 64 + tid]; }

    const int K = 2048;
    const int rl = lane & 15;
    const int kg = (lane >> 4) * 8;
    const __bf16* Abase = Efrag + (((size_t)(tb * 4 + wid) * 64) * 64 + lane) * 8;
    const __bf16* Bp = Bsw + (size_t)(hb * 64) * K;

    f32x4 acc[4] = {};

    for (int t = 0; t < 32; ++t) {
        const int k0 = t * 64;
        #pragma unroll
        for (int j = 0; j < 2; ++j) {
            int c = tid + j * 256;
            int row_ = c >> 3, cc_ = c & 7;
            const __bf16* s_ = Bp + (size_t)row_ * K + k0 + cc_ * 8;
            __builtin_amdgcn_global_load_lds(
                (const __attribute__((address_space(1))) void*)s_,
                (__attribute__((address_space(3))) void*)((char*)&Bs[0][0] + c * 16),
                16, 0, 0);
        }
        bf16x8 af[2];
        #pragma unroll
        for (int kk = 0; kk < 2; ++kk)
            af[kk] = *(const bf16x8*)(Abase + ((size_t)(t * 2 + kk) * 64) * 8);

        __syncthreads();

        #pragma unroll
        for (int kk = 0; kk < 2; ++kk) {
            bf16x8 bfm[4];
            const int kb = (kg + kk * 32) * 2;
            #pragma unroll
            for (int ni = 0; ni < 4; ++ni) {
                int r_ = ni * 16 + rl;
                bfm[ni] = *(const bf16x8*)((const char*)&Bs[0][0] + r_ * 128 + (kb ^ ((r_ & 7) << 4)));
            }
            #pragma unroll
            for (int ni = 0; ni < 4; ++ni)
                acc[ni] = __builtin_amdgcn_mfma_f32_16x16x32_bf16(
                    af[kk], bfm[ni], acc[ni], 0, 0, 0);
        }
        __syncthreads();
    }

    const int rg = lane >> 4;
    {
        float sr[4] = {0.f, 0.f, 0.f, 0.f};
        #pragma unroll
        for (int ni = 0; ni < 4; ++ni) {
            int h = ni * 16 + rl;
            float wh = wayS[h];
            float ah = a3S[h];
            #pragma unroll
            for (int r = 0; r < 4; ++r)
                sr[r] += tanhf(wh + acc[ni][r]) * ah;
        }
        #pragma unroll
        for (int m = 1; m < 16; m <<= 1) {
            #pragma unroll
            for (int r = 0; r < 4; ++r)
                sr[r] += __shfl_xor(sr[r], m, 64);
        }
        if (rl == 0) {
            int t_ = tb * 64 + wid * 16 + rg * 4;
            #pragma unroll
            for (int r = 0; r < 4; ++r)
                gpart[hb * T + t_ + r] = sr[r];
        }
    }
}

// ---------------------------------------------------------------------------
// Softmax over gamma with on-the-fly partial reduction (proven r9/r11/r12).
// ---------------------------------------------------------------------------
__global__ __launch_bounds__(1024) void softmax_gamma_k(
    const float* __restrict__ gpart, float* __restrict__ outw)
{
    __shared__ float sred[16];
    __shared__ float sbcM, sbcS;
    int tid = threadIdx.x;
    float g[4];
    float m = -3.4e38f;
    #pragma unroll
    for (int p = 0; p < 4; ++p) {
        int t = tid + p * 1024;
        float s = 0.f;
        for (int hb = 0; hb < 32; ++hb) s += gpart[hb * T + t];
        g[p] = s;
        m = fmaxf(m, s);
    }
    #pragma unroll
    for (int sh = 32; sh; sh >>= 1) m = fmaxf(m, __shfl_xor(m, sh, 64));
    if ((tid & 63) == 0) sred[tid >> 6] = m;
    __syncthreads();
    if (tid == 0) {
        float mm = sred[0];
        for (int i = 1; i < 16; ++i) mm = fmaxf(mm, sred[i]);
        sbcM = mm;
    }
    __syncthreads();
    float mx = sbcM;
    float ssum = 0.f;
    #pragma unroll
    for (int p = 0; p < 4; ++p) { g[p] = expf(g[p] - mx); ssum += g[p]; }
    #pragma unroll
    for (int sh = 32; sh; sh >>= 1) ssum += __shfl_xor(ssum, sh, 64);
    __syncthreads();
    if ((tid & 63) == 0) sred[tid >> 6] = ssum;
    __syncthreads();
    if (tid == 0) {
        float ss = 0.f;
        for (int i = 0; i < 16; ++i) ss += sred[i];
        sbcS = ss;
    }
    __syncthreads();
    float inv = 1.f / sbcS;
    #pragma unroll
    for (int p = 0; p < 4; ++p) outw[tid + p * 1024] = g[p] * inv;
}

// ---------------------------------------------------------------------------
// attn_applied[h] += sum_t w[t] * E[t,h] (fp32 E; acc zeroed by cvt_frag_k)
// ---------------------------------------------------------------------------
__global__ __launch_bounds__(256) void attn_apply_k(
    const float* __restrict__ E, const float* __restrict__ w,
    float* __restrict__ outacc)
{
    int tid = threadIdx.x;
    int t0 = blockIdx.x * 32;
    float a[8] = {0.f, 0.f, 0.f, 0.f, 0.f, 0.f, 0.f, 0.f};
    for (int t = t0; t < t0 + 32; ++t) {
        float wt = w[t];
        const float* Er = E + (size_t)t * H;
        #pragma unroll
        for (int j = 0; j < 8; ++j)
            a[j] += wt * Er[tid + 256 * j];
    }
    #pragma unroll
    for (int j = 0; j < 8; ++j)
        atomicAdd(&outacc[tid + 256 * j], a[j]);
}

// ---------------------------------------------------------------------------
// GRU gate combine (proven r1-r8): h_new = (1-z)*n + z*h0
// ---------------------------------------------------------------------------
__global__ __launch_bounds__(256) void gru_combine_k(
    const float* __restrict__ gi, const float* __restrict__ gh,
    const float* __restrict__ h0, float* __restrict__ hout)
{
    int h = blockIdx.x * 256 + threadIdx.x;
    float ir = gi[h], iz = gi[H + h], in_ = gi[2 * H + h];
    float hr = gh[h], hz = gh[H + h], hn = gh[2 * H + h];
    float r = 1.f / (1.f + expf(-(ir + hr)));
    float z = 1.f / (1.f + expf(-(iz + hz)));
    float n = tanhf(in_ + r * hn);
    hout[h] = (1.f - z) * n + z * h0[h];
}

// ---------------------------------------------------------------------------
// Small generic softmax (final output, n=1024).
// ---------------------------------------------------------------------------
__global__ __launch_bounds__(1024) void softmax_k(
    const float* __restrict__ in, float* __restrict__ out, int n)
{
    __shared__ float sred[16];
    __shared__ float sbc;
    int tid = threadIdx.x;

    float m = -3.4e38f;
    for (int i = tid; i < n; i += 1024) m = fmaxf(m, in[i]);
    #pragma unroll
    for (int s = 32; s; s >>= 1) m = fmaxf(m, __shfl_xor(m, s, 64));
    if ((tid & 63) == 0) sred[tid >> 6] = m;
    __syncthreads();
    if (tid == 0) {
        float mm = sred[0];
        for (int i = 1; i < 16; ++i) mm = fmaxf(mm, sred[i]);
        sbc = mm;
    }
    __syncthreads();
    float mx = sbc;

    float s = 0.f;
    for (int i = tid; i < n; i += 1024) s += expf(in[i] - mx);
    #pragma unroll
    for (int sh = 32; sh; sh >>= 1) s += __shfl_xor(s, sh, 64);
    if ((tid & 63) == 0) sred[tid >> 6] = s;
    __syncthreads();
    if (tid == 0) {
        float ss = 0.f;
        for (int i = 0; i < 16; ++i) ss += sred[i];
        sbc = ss;
    }
    __syncthreads();
    float inv = 1.f / sbc;
    for (int i = tid; i < n; i += 1024) out[i] = expf(in[i] - mx) * inv;
}

// ---------------------------------------------------------------------------
// Fallback fp32-staged gamma GEMM (used only if ws too small).
// ---------------------------------------------------------------------------
#define BM 128
#define BN 128
#define BK 32
#define LSTR 40

__global__ __launch_bounds__(256) void gamma_gemm(
    const float* __restrict__ E, const float* __restrict__ W2,
    const float* __restrict__ way, const float* __restrict__ a3,
    float* __restrict__ gamma)
{
    __shared__ __bf16 As[BM][LSTR];
    __shared__ __bf16 Bs[BN][LSTR];
    __shared__ float wayS[BN];
    __shared__ float a3S[BN];

    const int tb = blockIdx.x, hb = blockIdx.y;
    const int tid = threadIdx.x, lane = tid & 63, wid = tid >> 6;
    const int wr = wid >> 1, wc = wid & 1;
    if (tid < BN) { wayS[tid] = way[hb * BN + tid]; a3S[tid] = a3[hb * BN + tid]; }

    f32x4 acc[4][4] = {};
    const int K = 2048;
    const float* Ep  = E  + (size_t)(tb * BM) * K;
    const float* W2p = W2 + (size_t)(hb * BN) * K;
    const int rl = lane & 15;
    const int kg = (lane >> 4) * 8;

    for (int k0 = 0; k0 < K; k0 += BK) {
        __syncthreads();
        #pragma unroll
        for (int i = 0; i < 4; ++i) {
            int c = tid + i * 256;
            int row = c >> 3;
            int col = (c & 7) * 4;
            float4 va = *(const float4*)(Ep + (size_t)row * K + k0 + col);
            bf16x4 pa = {(__bf16)va.x, (__bf16)va.y, (__bf16)va.z, (__bf16)va.w};
            *(bf16x4*)&As[row][col] = pa;
            float4 vb = *(const float4*)(W2p + (size_t)row * K + k0 + col);
            bf16x4 pb = {(__bf16)vb.x, (__bf16)vb.y, (__bf16)vb.z, (__bf16)vb.w};
            *(bf16x4*)&Bs[row][col] = pb;
        }
        __syncthreads();
        bf16x8 af[4], bfr[4];
        #pragma unroll
        for (int mi = 0; mi < 4; ++mi)
            af[mi] = *(const bf16x8*)&As[wr * 64 + mi * 16 + rl][kg];
        #pragma unroll
        for (int ni = 0; ni < 4; ++ni)
            bfr[ni] = *(const bf16x8*)&Bs[wc * 64 + ni * 16 + rl][kg];
        #pragma unroll
        for (int mi = 0; mi < 4; ++mi)
            #pragma unroll
            for (int ni = 0; ni < 4; ++ni)
                acc[mi][ni] = __builtin_amdgcn_mfma_f32_16x16x32_bf16(
                    af[mi], bfr[ni], acc[mi][ni], 0, 0, 0);
    }

    const int rg = lane >> 4;
    #pragma unroll
    for (int mi = 0; mi < 4; ++mi) {
        float sr[4] = {0.f, 0.f, 0.f, 0.f};
        #pragma unroll
        for (int ni = 0; ni < 4; ++ni) {
            int h = wc * 64 + ni * 16 + rl;
            float wh = wayS[h];
            float ah = a3S[h];
            #pragma unroll
            for (int r = 0; r < 4; ++r)
                sr[r] += tanhf(wh + acc[mi][ni][r]) * ah;
        }
        #pragma unroll
        for (int m = 1; m < 16; m <<= 1) {
            #pragma unroll
            for (int r = 0; r < 4; ++r)
                sr[r] += __shfl_xor(sr[r], m, 64);
        }
        if (rl == 0) {
            int t = tb * BM + wr * 64 + mi * 16 + rg * 4;
            #pragma unroll
            for (int r = 0; r < 4; ++r)
                atomicAdd(&gamma[t + r], sr[r]);
        }
    }
}

// ---------------------------------------------------------------------------
extern "C" void kernel_launch(void* const* d_in, const int* in_sizes, int n_in,
                              void* d_out, int out_size, void* d_ws, size_t ws_size,
                              hipStream_t stream)
{
    const float* input    = (const float*)d_in[0];
    const float* hidden   = (const float*)d_in[1];
    const float* enc      = (const float*)d_in[2];
    const float* prenet_w = (const float*)d_in[3];
    const float* prenet_b = (const float*)d_in[4];
    const float* prenet2_w= (const float*)d_in[5];
    const float* prenet2_b= (const float*)d_in[6];
    const float* attn1_w  = (const float*)d_in[7];
    const float* attn2_w  = (const float*)d_in[8];
    const float* attn3_w  = (const float*)d_in[9];
    const float* gru_w_ih = (const float*)d_in[10];
    const float* gru_w_hh = (const float*)d_in[11];
    const float* gru_b_ih = (const float*)d_in[12];
    const float* gru_b_hh = (const float*)d_in[13];
    const float* lin_w    = (const float*)d_in[14];
    const float* lin_b    = (const float*)d_in[15];

    float* out = (float*)d_out;
    float* h_new = out + OUTN;
    float* attn_w = out + OUTN + H;

    float* ws = (float*)d_ws;
    float* w_h1     = ws;                 // 512
    float* w_way    = w_h1 + 512;         // 2048
    float* w_x      = w_way + H;          // 4096 (em6 ++ attn_applied)
    float* w_logits = w_x + 2 * H;        // 1024
    float* w_gi     = w_logits + OUTN;    // 6144
    float* w_gh     = w_gi + 3 * H;       // 6144
    float* w_gpart  = w_gh + 3 * H;       // 32*4096 (also fallback gamma)

    const size_t BF_OFF = 1 << 20;
    const size_t BF_BYTES = (size_t)(T + H) * H * sizeof(__bf16);
    bool fast = (ws_size >= BF_OFF + BF_BYTES);
    __bf16* bfE  = (__bf16*)((char*)d_ws + BF_OFF);   // fragment-major Efrag
    __bf16* bfW2 = bfE + (size_t)T * H;               // swizzled W2

    if (fast) {
        cvt_frag_k<<<(T + H) * (H / 8) / 256, 256, 0, stream>>>(enc, attn2_w, bfE, w_x + H);
    } else {
        hipMemsetAsync(w_x + H, 0, H * sizeof(float), stream);
    }

    matvec_k<<<H1 / 4, 256, 0, stream>>>(prenet_w, input, prenet_b, w_h1, H1, OUTN, 1);
    matvec_k<<<H / 4, 256, 0, stream>>>(prenet2_w, w_h1, prenet2_b, w_x, H, H1, 1);
    matvec_k<<<H / 4, 256, 0, stream>>>(attn1_w, w_x, nullptr, w_way, H, H, 0);

    if (fast) {
        gamma_gemm11<<<dim3(T / 64, H / 64), 256, 0, stream>>>(bfE, bfW2, w_way, attn3_w, w_gpart);
        softmax_gamma_k<<<1, 1024, 0, stream>>>(w_gpart, attn_w);
    } else {
        hipMemsetAsync(w_gpart, 0, T * sizeof(float), stream);
        gamma_gemm<<<dim3(T / BM, H / BN), 256, 0, stream>>>(enc, attn2_w, w_way, attn3_w, w_gpart);
        softmax_k<<<1, 1024, 0, stream>>>(w_gpart, attn_w, T);
    }

    attn_apply_k<<<T / 32, 256, 0, stream>>>(enc, attn_w, w_x + H);
    // GRU: proven 3-dispatch trio with wide-load matvecs for the big weights
    matvec_wide_k<<<(3 * H) / 4, 256, 0, stream>>>(gru_w_ih, w_x, gru_b_ih, w_gi, 3 * H, 2 * H);
    matvec_wide_k<<<(3 * H) / 4, 256, 0, stream>>>(gru_w_hh, hidden, gru_b_hh, w_gh, 3 * H, H);
    gru_combine_k<<<H / 256, 256, 0, stream>>>(w_gi, w_gh, hidden, h_new);
    matvec_k<<<OUTN / 4, 256, 0, stream>>>(lin_w, h_new, lin_b, w_logits, OUTN, H, 0);
    softmax_k<<<1, 1024, 0, stream>>>(w_logits, out, OUTN);
}

// Round 14
// 159.398 us; speedup vs baseline: 1.0201x; 1.0201x over previous
//
#include <hip/hip_runtime.h>
#include <hip/hip_bf16.h>

typedef __bf16 bf16x8 __attribute__((ext_vector_type(8)));
typedef __bf16 bf16x4 __attribute__((ext_vector_type(4)));
typedef float f32x4 __attribute__((ext_vector_type(4)));

#define H1 512
#define H 2048
#define OUTN 1024
#define T 4096

// ---------------------------------------------------------------------------
// matvec2: 512 threads = 8 waves; 4 rows/block, 2 waves per row (each wave
// does one K-half with lane-contiguous float4 loads -- the PROVEN coalescing
// pattern -- then LDS pair-combine). 2x waves/CU vs matvec_k.
// ---------------------------------------------------------------------------
__global__ __launch_bounds__(512) void matvec2_k(
    const float* __restrict__ W, const float* __restrict__ x,
    const float* __restrict__ b, float* __restrict__ out,
    int R, int K, int relu)
{
    __shared__ float part[8];
    const int wid = threadIdx.x >> 6;   // 0..7
    const int lane = threadIdx.x & 63;
    const int rloc = wid >> 1;          // 0..3
    const int half = wid & 1;
    const int row = blockIdx.x * 4 + rloc;
    if (row < R) {
        const float* Wr = W + (size_t)row * K;
        const int kbeg = half * (K >> 1);
        const int kend = kbeg + (K >> 1);
        float s = 0.f;
        for (int k = kbeg + lane * 4; k < kend; k += 256) {
            float4 w4 = *(const float4*)(Wr + k);
            float4 x4 = *(const float4*)(x + k);
            s += w4.x * x4.x + w4.y * x4.y + w4.z * x4.z + w4.w * x4.w;
        }
        #pragma unroll
        for (int m = 32; m; m >>= 1) s += __shfl_xor(s, m, 64);
        if (lane == 0) part[wid] = s;
    }
    __syncthreads();
    if (threadIdx.x < 4) {
        int r2 = blockIdx.x * 4 + (int)threadIdx.x;
        if (r2 < R) {
            float s = part[threadIdx.x * 2] + part[threadIdx.x * 2 + 1];
            if (b) s += b[r2];
            if (relu) s = fmaxf(s, 0.f);
            out[r2] = s;
        }
    }
}

// ---------------------------------------------------------------------------
// Generic row-wise matvec (fallback path only).
// ---------------------------------------------------------------------------
__global__ __launch_bounds__(256) void matvec_k(
    const float* __restrict__ W, const float* __restrict__ x,
    const float* __restrict__ b, float* __restrict__ out,
    int R, int K, int relu)
{
    int row = blockIdx.x * 4 + (threadIdx.x >> 6);
    int lane = threadIdx.x & 63;
    if (row >= R) return;
    const float* Wr = W + (size_t)row * K;
    float s = 0.f;
    for (int k = lane * 4; k < K; k += 256) {
        float4 w4 = *(const float4*)(Wr + k);
        float4 x4 = *(const float4*)(x + k);
        s += w4.x * x4.x + w4.y * x4.y + w4.z * x4.z + w4.w * x4.w;
    }
    #pragma unroll
    for (int m = 32; m; m >>= 1) s += __shfl_xor(s, m, 64);
    if (lane == 0) {
        if (b) s += b[row];
        if (relu) s = fmaxf(s, 0.f);
        out[row] = s;
    }
}

// ---------------------------------------------------------------------------
// One-shot fp32 -> bf16 convert (proven r7-r13).
// E: FRAGMENT-MAJOR Efrag[r16][k32][lane][8] (MFMA A-operand lane order).
// attn2_w: XOR-swizzled rows (chunk cc -> slot cc^(row&7) per 64-col group).
// Block 0 additionally zeroes the attn_applied accumulator (8 KB).
// ---------------------------------------------------------------------------
__global__ __launch_bounds__(256) void cvt_frag_k(
    const float* __restrict__ E, const float* __restrict__ W2,
    __bf16* __restrict__ dst, float* __restrict__ zero_acc)
{
    if (blockIdx.x == 0) {
        #pragma unroll
        for (int j = 0; j < 8; ++j)
            zero_acc[threadIdx.x + 256 * j] = 0.f;
    }
    const int EC = T * H / 8;
    int c = blockIdx.x * 256 + threadIdx.x;
    const float* src;
    __bf16* d;
    if (c < EC) {
        int lane = c & 63;
        int k32 = (c >> 6) & 63;
        int r16 = c >> 12;
        int row = r16 * 16 + (lane & 15);
        int col = k32 * 32 + (lane >> 4) * 8;
        src = E + (size_t)row * H + col;
        d = dst + (size_t)c * 8;
    } else {
        int c2 = c - EC;
        int row = c2 >> 8;
        int kc = c2 & 255;
        src = W2 + (size_t)row * H + kc * 8;
        int grp = kc >> 3, cc = kc & 7;
        int sw = cc ^ (row & 7);
        d = dst + (size_t)T * H + (size_t)row * H + grp * 64 + sw * 8;
    }
    float4 a = *(const float4*)src;
    float4 b = *(const float4*)(src + 4);
    bf16x8 v = {(__bf16)a.x, (__bf16)a.y, (__bf16)a.z, (__bf16)a.w,
                (__bf16)b.x, (__bf16)b.y, (__bf16)b.z, (__bf16)b.w};
    *(bf16x8*)d = v;
}

// ---------------------------------------------------------------------------
// gamma GEMM v11 (proven r11-r13): 64x64 tile, 4 waves pure-m, 2048 blocks =
// 8/CU full occupancy, frag-major A direct to VGPR, swizzled B-LDS,
// partial-write epilogue. Writes gpart[hb][t].
// ---------------------------------------------------------------------------
__global__ __launch_bounds__(256, 8) void gamma_gemm11(
    const __bf16* __restrict__ Efrag,  // [T/16][64][64][8] fragment-major
    const __bf16* __restrict__ Bsw,    // [H][2048] swizzled bf16
    const float* __restrict__ way, const float* __restrict__ a3,
    float* __restrict__ gpart)         // [H/64][T]
{
    __shared__ __attribute__((aligned(16))) __bf16 Bs[64][64];   // 8 KB
    __shared__ float wayS[64], a3S[64];

    const int tb = blockIdx.x, hb = blockIdx.y;
    const int tid = threadIdx.x, lane = tid & 63, wid = tid >> 6;
    if (tid < 64) { wayS[tid] = way[hb * 64 + tid]; a3S[tid] = a3[hb * 64 + tid]; }

    const int K = 2048;
    const int rl = lane & 15;
    const int kg = (lane >> 4) * 8;
    const __bf16* Abase = Efrag + (((size_t)(tb * 4 + wid) * 64) * 64 + lane) * 8;
    const __bf16* Bp = Bsw + (size_t)(hb * 64) * K;

    f32x4 acc[4] = {};

    for (int t = 0; t < 32; ++t) {
        const int k0 = t * 64;
        #pragma unroll
        for (int j = 0; j < 2; ++j) {
            int c = tid + j * 256;
            int row_ = c >> 3, cc_ = c & 7;
            const __bf16* s_ = Bp + (size_t)row_ * K + k0 + cc_ * 8;
            __builtin_amdgcn_global_load_lds(
                (const __attribute__((address_space(1))) void*)s_,
                (__attribute__((address_space(3))) void*)((char*)&Bs[0][0] + c * 16),
                16, 0, 0);
        }
        bf16x8 af[2];
        #pragma unroll
        for (int kk = 0; kk < 2; ++kk)
            af[kk] = *(const bf16x8*)(Abase + ((size_t)(t * 2 + kk) * 64) * 8);

        __syncthreads();

        #pragma unroll
        for (int kk = 0; kk < 2; ++kk) {
            bf16x8 bfm[4];
            const int kb = (kg + kk * 32) * 2;
            #pragma unroll
            for (int ni = 0; ni < 4; ++ni) {
                int r_ = ni * 16 + rl;
                bfm[ni] = *(const bf16x8*)((const char*)&Bs[0][0] + r_ * 128 + (kb ^ ((r_ & 7) << 4)));
            }
            #pragma unroll
            for (int ni = 0; ni < 4; ++ni)
                acc[ni] = __builtin_amdgcn_mfma_f32_16x16x32_bf16(
                    af[kk], bfm[ni], acc[ni], 0, 0, 0);
        }
        __syncthreads();
    }

    const int rg = lane >> 4;
    {
        float sr[4] = {0.f, 0.f, 0.f, 0.f};
        #pragma unroll
        for (int ni = 0; ni < 4; ++ni) {
            int h = ni * 16 + rl;
            float wh = wayS[h];
            float ah = a3S[h];
            #pragma unroll
            for (int r = 0; r < 4; ++r)
                sr[r] += tanhf(wh + acc[ni][r]) * ah;
        }
        #pragma unroll
        for (int m = 1; m < 16; m <<= 1) {
            #pragma unroll
            for (int r = 0; r < 4; ++r)
                sr[r] += __shfl_xor(sr[r], m, 64);
        }
        if (rl == 0) {
            int t_ = tb * 64 + wid * 16 + rg * 4;
            #pragma unroll
            for (int r = 0; r < 4; ++r)
                gpart[hb * T + t_ + r] = sr[r];
        }
    }
}

// ---------------------------------------------------------------------------
// Softmax over gamma with on-the-fly partial reduction (proven r8-r13).
// ---------------------------------------------------------------------------
__global__ __launch_bounds__(1024) void softmax_gamma_k(
    const float* __restrict__ gpart, float* __restrict__ outw)
{
    __shared__ float sred[16];
    __shared__ float sbcM, sbcS;
    int tid = threadIdx.x;
    float g[4];
    float m = -3.4e38f;
    #pragma unroll
    for (int p = 0; p < 4; ++p) {
        int t = tid + p * 1024;
        float s = 0.f;
        for (int hb = 0; hb < 32; ++hb) s += gpart[hb * T + t];
        g[p] = s;
        m = fmaxf(m, s);
    }
    #pragma unroll
    for (int sh = 32; sh; sh >>= 1) m = fmaxf(m, __shfl_xor(m, sh, 64));
    if ((tid & 63) == 0) sred[tid >> 6] = m;
    __syncthreads();
    if (tid == 0) {
        float mm = sred[0];
        for (int i = 1; i < 16; ++i) mm = fmaxf(mm, sred[i]);
        sbcM = mm;
    }
    __syncthreads();
    float mx = sbcM;
    float ssum = 0.f;
    #pragma unroll
    for (int p = 0; p < 4; ++p) { g[p] = expf(g[p] - mx); ssum += g[p]; }
    #pragma unroll
    for (int sh = 32; sh; sh >>= 1) ssum += __shfl_xor(ssum, sh, 64);
    __syncthreads();
    if ((tid & 63) == 0) sred[tid >> 6] = ssum;
    __syncthreads();
    if (tid == 0) {
        float ss = 0.f;
        for (int i = 0; i < 16; ++i) ss += sred[i];
        sbcS = ss;
    }
    __syncthreads();
    float inv = 1.f / sbcS;
    #pragma unroll
    for (int p = 0; p < 4; ++p) outw[tid + p * 1024] = g[p] * inv;
}

// ---------------------------------------------------------------------------
// attn_applied[h] += sum_t w[t] * E[t,h] (fp32 E; acc zeroed by cvt_frag_k)
// ---------------------------------------------------------------------------
__global__ __launch_bounds__(256) void attn_apply_k(
    const float* __restrict__ E, const float* __restrict__ w,
    float* __restrict__ outacc)
{
    int tid = threadIdx.x;
    int t0 = blockIdx.x * 32;
    float a[8] = {0.f, 0.f, 0.f, 0.f, 0.f, 0.f, 0.f, 0.f};
    for (int t = t0; t < t0 + 32; ++t) {
        float wt = w[t];
        const float* Er = E + (size_t)t * H;
        #pragma unroll
        for (int j = 0; j < 8; ++j)
            a[j] += wt * Er[tid + 256 * j];
    }
    #pragma unroll
    for (int j = 0; j < 8; ++j)
        atomicAdd(&outacc[tid + 256 * j], a[j]);
}

// ---------------------------------------------------------------------------
// GRU gate combine (proven r1-r10): h_new = (1-z)*n + z*h0
// ---------------------------------------------------------------------------
__global__ __launch_bounds__(256) void gru_combine_k(
    const float* __restrict__ gi, const float* __restrict__ gh,
    const float* __restrict__ h0, float* __restrict__ hout)
{
    int h = blockIdx.x * 256 + threadIdx.x;
    float ir = gi[h], iz = gi[H + h], in_ = gi[2 * H + h];
    float hr = gh[h], hz = gh[H + h], hn = gh[2 * H + h];
    float r = 1.f / (1.f + expf(-(ir + hr)));
    float z = 1.f / (1.f + expf(-(iz + hz)));
    float n = tanhf(in_ + r * hn);
    hout[h] = (1.f - z) * n + z * h0[h];
}

// ---------------------------------------------------------------------------
// Small generic softmax (final output, n=1024).
// ---------------------------------------------------------------------------
__global__ __launch_bounds__(1024) void softmax_k(
    const float* __restrict__ in, float* __restrict__ out, int n)
{
    __shared__ float sred[16];
    __shared__ float sbc;
    int tid = threadIdx.x;

    float m = -3.4e38f;
    for (int i = tid; i < n; i += 1024) m = fmaxf(m, in[i]);
    #pragma unroll
    for (int s = 32; s; s >>= 1) m = fmaxf(m, __shfl_xor(m, s, 64));
    if ((tid & 63) == 0) sred[tid >> 6] = m;
    __syncthreads();
    if (tid == 0) {
        float mm = sred[0];
        for (int i = 1; i < 16; ++i) mm = fmaxf(mm, sred[i]);
        sbc = mm;
    }
    __syncthreads();
    float mx = sbc;

    float s = 0.f;
    for (int i = tid; i < n; i += 1024) s += expf(in[i] - mx);
    #pragma unroll
    for (int sh = 32; sh; sh >>= 1) s += __shfl_xor(s, sh, 64);
    if ((tid & 63) == 0) sred[tid >> 6] = s;
    __syncthreads();
    if (tid == 0) {
        float ss = 0.f;
        for (int i = 0; i < 16; ++i) ss += sred[i];
        sbc = ss;
    }
    __syncthreads();
    float inv = 1.f / sbc;
    for (int i = tid; i < n; i += 1024) out[i] = expf(in[i] - mx) * inv;
}

// ---------------------------------------------------------------------------
// Fallback fp32-staged gamma GEMM (used only if ws too small).
// ---------------------------------------------------------------------------
#define BM 128
#define BN 128
#define BK 32
#define LSTR 40

__global__ __launch_bounds__(256) void gamma_gemm(
    const float* __restrict__ E, const float* __restrict__ W2,
    const float* __restrict__ way, const float* __restrict__ a3,
    float* __restrict__ gamma)
{
    __shared__ __bf16 As[BM][LSTR];
    __shared__ __bf16 Bs[BN][LSTR];
    __shared__ float wayS[BN];
    __shared__ float a3S[BN];

    const int tb = blockIdx.x, hb = blockIdx.y;
    const int tid = threadIdx.x, lane = tid & 63, wid = tid >> 6;
    const int wr = wid >> 1, wc = wid & 1;
    if (tid < BN) { wayS[tid] = way[hb * BN + tid]; a3S[tid] = a3[hb * BN + tid]; }

    f32x4 acc[4][4] = {};
    const int K = 2048;
    const float* Ep  = E  + (size_t)(tb * BM) * K;
    const float* W2p = W2 + (size_t)(hb * BN) * K;
    const int rl = lane & 15;
    const int kg = (lane >> 4) * 8;

    for (int k0 = 0; k0 < K; k0 += BK) {
        __syncthreads();
        #pragma unroll
        for (int i = 0; i < 4; ++i) {
            int c = tid + i * 256;
            int row = c >> 3;
            int col = (c & 7) * 4;
            float4 va = *(const float4*)(Ep + (size_t)row * K + k0 + col);
            bf16x4 pa = {(__bf16)va.x, (__bf16)va.y, (__bf16)va.z, (__bf16)va.w};
            *(bf16x4*)&As[row][col] = pa;
            float4 vb = *(const float4*)(W2p + (size_t)row * K + k0 + col);
            bf16x4 pb = {(__bf16)vb.x, (__bf16)vb.y, (__bf16)vb.z, (__bf16)vb.w};
            *(bf16x4*)&Bs[row][col] = pb;
        }
        __syncthreads();
        bf16x8 af[4], bfr[4];
        #pragma unroll
        for (int mi = 0; mi < 4; ++mi)
            af[mi] = *(const bf16x8*)&As[wr * 64 + mi * 16 + rl][kg];
        #pragma unroll
        for (int ni = 0; ni < 4; ++ni)
            bfr[ni] = *(const bf16x8*)&Bs[wc * 64 + ni * 16 + rl][kg];
        #pragma unroll
        for (int mi = 0; mi < 4; ++mi)
            #pragma unroll
            for (int ni = 0; ni < 4; ++ni)
                acc[mi][ni] = __builtin_amdgcn_mfma_f32_16x16x32_bf16(
                    af[mi], bfr[ni], acc[mi][ni], 0, 0, 0);
    }

    const int rg = lane >> 4;
    #pragma unroll
    for (int mi = 0; mi < 4; ++mi) {
        float sr[4] = {0.f, 0.f, 0.f, 0.f};
        #pragma unroll
        for (int ni = 0; ni < 4; ++ni) {
            int h = wc * 64 + ni * 16 + rl;
            float wh = wayS[h];
            float ah = a3S[h];
            #pragma unroll
            for (int r = 0; r < 4; ++r)
                sr[r] += tanhf(wh + acc[mi][ni][r]) * ah;
        }
        #pragma unroll
        for (int m = 1; m < 16; m <<= 1) {
            #pragma unroll
            for (int r = 0; r < 4; ++r)
                sr[r] += __shfl_xor(sr[r], m, 64);
        }
        if (rl == 0) {
            int t = tb * BM + wr * 64 + mi * 16 + rg * 4;
            #pragma unroll
            for (int r = 0; r < 4; ++r)
                atomicAdd(&gamma[t + r], sr[r]);
        }
    }
}

// ---------------------------------------------------------------------------
extern "C" void kernel_launch(void* const* d_in, const int* in_sizes, int n_in,
                              void* d_out, int out_size, void* d_ws, size_t ws_size,
                              hipStream_t stream)
{
    const float* input    = (const float*)d_in[0];
    const float* hidden   = (const float*)d_in[1];
    const float* enc      = (const float*)d_in[2];
    const float* prenet_w = (const float*)d_in[3];
    const float* prenet_b = (const float*)d_in[4];
    const float* prenet2_w= (const float*)d_in[5];
    const float* prenet2_b= (const float*)d_in[6];
    const float* attn1_w  = (const float*)d_in[7];
    const float* attn2_w  = (const float*)d_in[8];
    const float* attn3_w  = (const float*)d_in[9];
    const float* gru_w_ih = (const float*)d_in[10];
    const float* gru_w_hh = (const float*)d_in[11];
    const float* gru_b_ih = (const float*)d_in[12];
    const float* gru_b_hh = (const float*)d_in[13];
    const float* lin_w    = (const float*)d_in[14];
    const float* lin_b    = (const float*)d_in[15];

    float* out = (float*)d_out;
    float* h_new = out + OUTN;
    float* attn_w = out + OUTN + H;

    float* ws = (float*)d_ws;
    float* w_h1     = ws;                 // 512
    float* w_way    = w_h1 + 512;         // 2048
    float* w_x      = w_way + H;          // 4096 (em6 ++ attn_applied)
    float* w_logits = w_x + 2 * H;        // 1024
    float* w_gi     = w_logits + OUTN;    // 6144
    float* w_gh     = w_gi + 3 * H;       // 6144
    float* w_gpart  = w_gh + 3 * H;       // 32*4096 (also fallback gamma)

    const size_t BF_OFF = 1 << 20;
    const size_t BF_BYTES = (size_t)(T + H) * H * sizeof(__bf16);
    bool fast = (ws_size >= BF_OFF + BF_BYTES);
    __bf16* bfE  = (__bf16*)((char*)d_ws + BF_OFF);   // fragment-major Efrag
    __bf16* bfW2 = bfE + (size_t)T * H;               // swizzled W2

    if (fast) {
        cvt_frag_k<<<(T + H) * (H / 8) / 256, 256, 0, stream>>>(enc, attn2_w, bfE, w_x + H);
    } else {
        hipMemsetAsync(w_x + H, 0, H * sizeof(float), stream);
    }

    matvec2_k<<<H1 / 4, 512, 0, stream>>>(prenet_w, input, prenet_b, w_h1, H1, OUTN, 1);
    matvec2_k<<<H / 4, 512, 0, stream>>>(prenet2_w, w_h1, prenet2_b, w_x, H, H1, 1);
    matvec2_k<<<H / 4, 512, 0, stream>>>(attn1_w, w_x, nullptr, w_way, H, H, 0);

    if (fast) {
        gamma_gemm11<<<dim3(T / 64, H / 64), 256, 0, stream>>>(bfE, bfW2, w_way, attn3_w, w_gpart);
        softmax_gamma_k<<<1, 1024, 0, stream>>>(w_gpart, attn_w);
    } else {
        hipMemsetAsync(w_gpart, 0, T * sizeof(float), stream);
        gamma_gemm<<<dim3(T / BM, H / BN), 256, 0, stream>>>(enc, attn2_w, w_way, attn3_w, w_gpart);
        softmax_k<<<1, 1024, 0, stream>>>(w_gpart, attn_w, T);
    }

    attn_apply_k<<<T / 32, 256, 0, stream>>>(enc, attn_w, w_x + H);
    // GRU: proven lane-contiguous trio, now with 2-waves-per-row matvecs
    matvec2_k<<<(3 * H) / 4, 512, 0, stream>>>(gru_w_ih, w_x, gru_b_ih, w_gi, 3 * H, 2 * H, 0);
    matvec2_k<<<(3 * H) / 4, 512, 0, stream>>>(gru_w_hh, hidden, gru_b_hh, w_gh, 3 * H, H, 0);
    gru_combine_k<<<H / 256, 256, 0, stream>>>(w_gi, w_gh, hidden, h_new);
    matvec2_k<<<OUTN / 4, 512, 0, stream>>>(lin_w, h_new, lin_b, w_logits, OUTN, H, 0);
    softmax_k<<<1, 1024, 0, stream>>>(w_logits, out, OUTN);
}

// Round 15
// 121.137 us; speedup vs baseline: 1.3423x; 1.3159x over previous
//
#include <hip/hip_runtime.h>
#include <hip/hip_bf16.h>

typedef __bf16 bf16x8 __attribute__((ext_vector_type(8)));
typedef __bf16 bf16x4 __attribute__((ext_vector_type(4)));
typedef float f32x4 __attribute__((ext_vector_type(4)));

#define H1 512
#define H 2048
#define OUTN 1024
#define T 4096

// ---------------------------------------------------------------------------
// Generic row-wise matvec (THE proven kernel: 4 waves/block, 1 wave/row,
// lane-contiguous float4). Do not "improve" -- wide(r13)/2-wave(r14)/fused
// (r11)/block(r12) variants all regressed.
// ---------------------------------------------------------------------------
__global__ __launch_bounds__(256) void matvec_k(
    const float* __restrict__ W, const float* __restrict__ x,
    const float* __restrict__ b, float* __restrict__ out,
    int R, int K, int relu)
{
    int row = blockIdx.x * 4 + (threadIdx.x >> 6);
    int lane = threadIdx.x & 63;
    if (row >= R) return;
    const float* Wr = W + (size_t)row * K;
    float s = 0.f;
    for (int k = lane * 4; k < K; k += 256) {
        float4 w4 = *(const float4*)(Wr + k);
        float4 x4 = *(const float4*)(x + k);
        s += w4.x * x4.x + w4.y * x4.y + w4.z * x4.z + w4.w * x4.w;
    }
    #pragma unroll
    for (int m = 32; m; m >>= 1) s += __shfl_xor(s, m, 64);
    if (lane == 0) {
        if (b) s += b[row];
        if (relu) s = fmaxf(s, 0.f);
        out[row] = s;
    }
}

// ---------------------------------------------------------------------------
// One-shot fp32 -> bf16 convert (proven r7-r14).
// E: FRAGMENT-MAJOR Efrag[r16][k32][lane][8] (MFMA A-operand lane order).
// attn2_w: XOR-swizzled rows (chunk cc -> slot cc^(row&7) per 64-col group).
// Block 0 additionally zeroes the attn_applied accumulator (8 KB); this
// kernel precedes attn_apply on the same stream, so ordering is guaranteed.
// ---------------------------------------------------------------------------
__global__ __launch_bounds__(256) void cvt_frag_k(
    const float* __restrict__ E, const float* __restrict__ W2,
    __bf16* __restrict__ dst, float* __restrict__ zero_acc)
{
    if (blockIdx.x == 0) {
        #pragma unroll
        for (int j = 0; j < 8; ++j)
            zero_acc[threadIdx.x + 256 * j] = 0.f;
    }
    const int EC = T * H / 8;
    int c = blockIdx.x * 256 + threadIdx.x;
    const float* src;
    __bf16* d;
    if (c < EC) {
        int lane = c & 63;
        int k32 = (c >> 6) & 63;
        int r16 = c >> 12;
        int row = r16 * 16 + (lane & 15);
        int col = k32 * 32 + (lane >> 4) * 8;
        src = E + (size_t)row * H + col;
        d = dst + (size_t)c * 8;
    } else {
        int c2 = c - EC;
        int row = c2 >> 8;
        int kc = c2 & 255;
        src = W2 + (size_t)row * H + kc * 8;
        int grp = kc >> 3, cc = kc & 7;
        int sw = cc ^ (row & 7);
        d = dst + (size_t)T * H + (size_t)row * H + grp * 64 + sw * 8;
    }
    float4 a = *(const float4*)src;
    float4 b = *(const float4*)(src + 4);
    bf16x8 v = {(__bf16)a.x, (__bf16)a.y, (__bf16)a.z, (__bf16)a.w,
                (__bf16)b.x, (__bf16)b.y, (__bf16)b.z, (__bf16)b.w};
    *(bf16x8*)d = v;
}

// ---------------------------------------------------------------------------
// gamma GEMM v8p: r8's champion main loop, byte-identical (128x64 tile,
// 4 waves pure-m, grid 32x32 = 1024 blocks = 4/CU, frag-major A direct to
// VGPR, single-buffered swizzled B-LDS via global_load_lds w16, conflict-
// free swizzled ds_read_b128, BK=64). ONLY the epilogue changed: clean
// partial write gpart[hb][t] instead of atomicAdd (verified r11-r14).
// ---------------------------------------------------------------------------
__global__ __launch_bounds__(256, 4) void gamma_gemm8p(
    const __bf16* __restrict__ Efrag,  // [T/16][64][64][8] fragment-major
    const __bf16* __restrict__ Bsw,    // [H][2048] swizzled bf16
    const float* __restrict__ way, const float* __restrict__ a3,
    float* __restrict__ gpart)         // [H/64][T]
{
    __shared__ __attribute__((aligned(16))) __bf16 Bs[64][64];   // 8 KB
    __shared__ float wayS[64], a3S[64];

    const int tb = blockIdx.x, hb = blockIdx.y;
    const int tid = threadIdx.x, lane = tid & 63, wid = tid >> 6;
    if (tid < 64) { wayS[tid] = way[hb * 64 + tid]; a3S[tid] = a3[hb * 64 + tid]; }

    const int K = 2048;
    const int rl = lane & 15;
    const int kg = (lane >> 4) * 8;
    const __bf16* Abase = Efrag + (((size_t)(tb * 8 + wid * 2) * 64) * 64 + lane) * 8;
    const __bf16* Bp = Bsw + (size_t)(hb * 64) * K;

    f32x4 acc[2][4] = {};

    for (int t = 0; t < 32; ++t) {
        const int k0 = t * 64;
        #pragma unroll
        for (int j = 0; j < 2; ++j) {
            int c = tid + j * 256;
            int row_ = c >> 3, cc_ = c & 7;
            const __bf16* s_ = Bp + (size_t)row_ * K + k0 + cc_ * 8;
            __builtin_amdgcn_global_load_lds(
                (const __attribute__((address_space(1))) void*)s_,
                (__attribute__((address_space(3))) void*)((char*)&Bs[0][0] + c * 16),
                16, 0, 0);
        }
        bf16x8 af[2][2];
        #pragma unroll
        for (int mi = 0; mi < 2; ++mi)
            #pragma unroll
            for (int kk = 0; kk < 2; ++kk)
                af[mi][kk] = *(const bf16x8*)(Abase +
                    ((size_t)(mi * 64 + t * 2 + kk) * 64) * 8);

        __syncthreads();

        #pragma unroll
        for (int kk = 0; kk < 2; ++kk) {
            bf16x8 bfm[4];
            const int kb = (kg + kk * 32) * 2;
            #pragma unroll
            for (int ni = 0; ni < 4; ++ni) {
                int r_ = ni * 16 + rl;
                bfm[ni] = *(const bf16x8*)((const char*)&Bs[0][0] + r_ * 128 + (kb ^ ((r_ & 7) << 4)));
            }
            #pragma unroll
            for (int mi = 0; mi < 2; ++mi)
                #pragma unroll
                for (int ni = 0; ni < 4; ++ni)
                    acc[mi][ni] = __builtin_amdgcn_mfma_f32_16x16x32_bf16(
                        af[mi][kk], bfm[ni], acc[mi][ni], 0, 0, 0);
        }
        __syncthreads();
    }

    // Epilogue: tanh + weighted reduce over h, clean partial write.
    // D layout: col = lane&15 (h), row = (lane>>4)*4 + r (t)
    const int rg = lane >> 4;
    #pragma unroll
    for (int mi = 0; mi < 2; ++mi) {
        float sr[4] = {0.f, 0.f, 0.f, 0.f};
        #pragma unroll
        for (int ni = 0; ni < 4; ++ni) {
            int h = ni * 16 + rl;
            float wh = wayS[h];
            float ah = a3S[h];
            #pragma unroll
            for (int r = 0; r < 4; ++r)
                sr[r] += tanhf(wh + acc[mi][ni][r]) * ah;
        }
        #pragma unroll
        for (int m = 1; m < 16; m <<= 1) {
            #pragma unroll
            for (int r = 0; r < 4; ++r)
                sr[r] += __shfl_xor(sr[r], m, 64);
        }
        if (rl == 0) {
            int t_ = tb * 128 + wid * 32 + mi * 16 + rg * 4;
            #pragma unroll
            for (int r = 0; r < 4; ++r)
                gpart[hb * T + t_ + r] = sr[r];
        }
    }
}

// ---------------------------------------------------------------------------
// PARALLEL gpart reduction: gamma[t] = sum_hb gpart[hb][t]. 16 blocks x 256
// threads across 16 CUs (vs softmax_gamma_k's single-CU serial chain, the
// r9-r14 regression). Coalesced 256B/wave/hb; 4-way unrolled for ILP.
// ---------------------------------------------------------------------------
__global__ __launch_bounds__(256) void gsum_k(
    const float* __restrict__ gpart, float* __restrict__ gamma)
{
    int t = blockIdx.x * 256 + threadIdx.x;
    float s0 = 0.f, s1 = 0.f, s2 = 0.f, s3 = 0.f;
    #pragma unroll
    for (int hb = 0; hb < 32; hb += 4) {
        s0 += gpart[(hb + 0) * T + t];
        s1 += gpart[(hb + 1) * T + t];
        s2 += gpart[(hb + 2) * T + t];
        s3 += gpart[(hb + 3) * T + t];
    }
    gamma[t] = (s0 + s1) + (s2 + s3);
}

// ---------------------------------------------------------------------------
// Single-block softmax (proven r1-r10): n <= 4096.
// ---------------------------------------------------------------------------
__global__ __launch_bounds__(1024) void softmax_k(
    const float* __restrict__ in, float* __restrict__ out, int n)
{
    __shared__ float sred[16];
    __shared__ float sbc;
    int tid = threadIdx.x;

    float m = -3.4e38f;
    for (int i = tid; i < n; i += 1024) m = fmaxf(m, in[i]);
    #pragma unroll
    for (int s = 32; s; s >>= 1) m = fmaxf(m, __shfl_xor(m, s, 64));
    if ((tid & 63) == 0) sred[tid >> 6] = m;
    __syncthreads();
    if (tid == 0) {
        float mm = sred[0];
        for (int i = 1; i < 16; ++i) mm = fmaxf(mm, sred[i]);
        sbc = mm;
    }
    __syncthreads();
    float mx = sbc;

    float s = 0.f;
    for (int i = tid; i < n; i += 1024) s += expf(in[i] - mx);
    #pragma unroll
    for (int sh = 32; sh; sh >>= 1) s += __shfl_xor(s, sh, 64);
    if ((tid & 63) == 0) sred[tid >> 6] = s;
    __syncthreads();
    if (tid == 0) {
        float ss = 0.f;
        for (int i = 0; i < 16; ++i) ss += sred[i];
        sbc = ss;
    }
    __syncthreads();
    float inv = 1.f / sbc;
    for (int i = tid; i < n; i += 1024) out[i] = expf(in[i] - mx) * inv;
}

// ---------------------------------------------------------------------------
// attn_applied[h] += sum_t w[t] * E[t,h] (fp32 E; acc zeroed by cvt_frag_k)
// ---------------------------------------------------------------------------
__global__ __launch_bounds__(256) void attn_apply_k(
    const float* __restrict__ E, const float* __restrict__ w,
    float* __restrict__ outacc)
{
    int tid = threadIdx.x;
    int t0 = blockIdx.x * 32;
    float a[8] = {0.f, 0.f, 0.f, 0.f, 0.f, 0.f, 0.f, 0.f};
    for (int t = t0; t < t0 + 32; ++t) {
        float wt = w[t];
        const float* Er = E + (size_t)t * H;
        #pragma unroll
        for (int j = 0; j < 8; ++j)
            a[j] += wt * Er[tid + 256 * j];
    }
    #pragma unroll
    for (int j = 0; j < 8; ++j)
        atomicAdd(&outacc[tid + 256 * j], a[j]);
}

// ---------------------------------------------------------------------------
// GRU gate combine (proven r1-r10): h_new = (1-z)*n + z*h0
// ---------------------------------------------------------------------------
__global__ __launch_bounds__(256) void gru_combine_k(
    const float* __restrict__ gi, const float* __restrict__ gh,
    const float* __restrict__ h0, float* __restrict__ hout)
{
    int h = blockIdx.x * 256 + threadIdx.x;
    float ir = gi[h], iz = gi[H + h], in_ = gi[2 * H + h];
    float hr = gh[h], hz = gh[H + h], hn = gh[2 * H + h];
    float r = 1.f / (1.f + expf(-(ir + hr)));
    float z = 1.f / (1.f + expf(-(iz + hz)));
    float n = tanhf(in_ + r * hn);
    hout[h] = (1.f - z) * n + z * h0[h];
}

// ---------------------------------------------------------------------------
// Fallback fp32-staged gamma GEMM (used only if ws too small).
// ---------------------------------------------------------------------------
#define BM 128
#define BN 128
#define BK 32
#define LSTR 40

__global__ __launch_bounds__(256) void gamma_gemm(
    const float* __restrict__ E, const float* __restrict__ W2,
    const float* __restrict__ way, const float* __restrict__ a3,
    float* __restrict__ gamma)
{
    __shared__ __bf16 As[BM][LSTR];
    __shared__ __bf16 Bs[BN][LSTR];
    __shared__ float wayS[BN];
    __shared__ float a3S[BN];

    const int tb = blockIdx.x, hb = blockIdx.y;
    const int tid = threadIdx.x, lane = tid & 63, wid = tid >> 6;
    const int wr = wid >> 1, wc = wid & 1;
    if (tid < BN) { wayS[tid] = way[hb * BN + tid]; a3S[tid] = a3[hb * BN + tid]; }

    f32x4 acc[4][4] = {};
    const int K = 2048;
    const float* Ep  = E  + (size_t)(tb * BM) * K;
    const float* W2p = W2 + (size_t)(hb * BN) * K;
    const int rl = lane & 15;
    const int kg = (lane >> 4) * 8;

    for (int k0 = 0; k0 < K; k0 += BK) {
        __syncthreads();
        #pragma unroll
        for (int i = 0; i < 4; ++i) {
            int c = tid + i * 256;
            int row = c >> 3;
            int col = (c & 7) * 4;
            float4 va = *(const float4*)(Ep + (size_t)row * K + k0 + col);
            bf16x4 pa = {(__bf16)va.x, (__bf16)va.y, (__bf16)va.z, (__bf16)va.w};
            *(bf16x4*)&As[row][col] = pa;
            float4 vb = *(const float4*)(W2p + (size_t)row * K + k0 + col);
            bf16x4 pb = {(__bf16)vb.x, (__bf16)vb.y, (__bf16)vb.z, (__bf16)vb.w};
            *(bf16x4*)&Bs[row][col] = pb;
        }
        __syncthreads();
        bf16x8 af[4], bfr[4];
        #pragma unroll
        for (int mi = 0; mi < 4; ++mi)
            af[mi] = *(const bf16x8*)&As[wr * 64 + mi * 16 + rl][kg];
        #pragma unroll
        for (int ni = 0; ni < 4; ++ni)
            bfr[ni] = *(const bf16x8*)&Bs[wc * 64 + ni * 16 + rl][kg];
        #pragma unroll
        for (int mi = 0; mi < 4; ++mi)
            #pragma unroll
            for (int ni = 0; ni < 4; ++ni)
                acc[mi][ni] = __builtin_amdgcn_mfma_f32_16x16x32_bf16(
                    af[mi], bfr[ni], acc[mi][ni], 0, 0, 0);
    }

    const int rg = lane >> 4;
    #pragma unroll
    for (int mi = 0; mi < 4; ++mi) {
        float sr[4] = {0.f, 0.f, 0.f, 0.f};
        #pragma unroll
        for (int ni = 0; ni < 4; ++ni) {
            int h = wc * 64 + ni * 16 + rl;
            float wh = wayS[h];
            float ah = a3S[h];
            #pragma unroll
            for (int r = 0; r < 4; ++r)
                sr[r] += tanhf(wh + acc[mi][ni][r]) * ah;
        }
        #pragma unroll
        for (int m = 1; m < 16; m <<= 1) {
            #pragma unroll
            for (int r = 0; r < 4; ++r)
                sr[r] += __shfl_xor(sr[r], m, 64);
        }
        if (rl == 0) {
            int t = tb * BM + wr * 64 + mi * 16 + rg * 4;
            #pragma unroll
            for (int r = 0; r < 4; ++r)
                atomicAdd(&gamma[t + r], sr[r]);
        }
    }
}

// ---------------------------------------------------------------------------
extern "C" void kernel_launch(void* const* d_in, const int* in_sizes, int n_in,
                              void* d_out, int out_size, void* d_ws, size_t ws_size,
                              hipStream_t stream)
{
    const float* input    = (const float*)d_in[0];
    const float* hidden   = (const float*)d_in[1];
    const float* enc      = (const float*)d_in[2];
    const float* prenet_w = (const float*)d_in[3];
    const float* prenet_b = (const float*)d_in[4];
    const float* prenet2_w= (const float*)d_in[5];
    const float* prenet2_b= (const float*)d_in[6];
    const float* attn1_w  = (const float*)d_in[7];
    const float* attn2_w  = (const float*)d_in[8];
    const float* attn3_w  = (const float*)d_in[9];
    const float* gru_w_ih = (const float*)d_in[10];
    const float* gru_w_hh = (const float*)d_in[11];
    const float* gru_b_ih = (const float*)d_in[12];
    const float* gru_b_hh = (const float*)d_in[13];
    const float* lin_w    = (const float*)d_in[14];
    const float* lin_b    = (const float*)d_in[15];

    float* out = (float*)d_out;
    float* h_new = out + OUTN;
    float* attn_w = out + OUTN + H;

    float* ws = (float*)d_ws;
    float* w_h1     = ws;                 // 512
    float* w_way    = w_h1 + 512;         // 2048
    float* w_x      = w_way + H;          // 4096 (em6 ++ attn_applied)
    float* w_logits = w_x + 2 * H;        // 1024
    float* w_gamma  = w_logits + OUTN;    // 4096
    float* w_gi     = w_gamma + T;        // 6144
    float* w_gh     = w_gi + 3 * H;       // 6144
    float* w_gpart  = w_gh + 3 * H;       // 32*4096 = 131072

    const size_t BF_OFF = 1 << 20;
    const size_t BF_BYTES = (size_t)(T + H) * H * sizeof(__bf16);   // 24 MB
    bool fast = (ws_size >= BF_OFF + BF_BYTES);
    __bf16* bfE  = (__bf16*)((char*)d_ws + BF_OFF);   // fragment-major Efrag
    __bf16* bfW2 = bfE + (size_t)T * H;               // swizzled W2

    if (fast) {
        // also zeroes w_x+H (attn_applied accumulator) in block 0
        cvt_frag_k<<<(T + H) * (H / 8) / 256, 256, 0, stream>>>(enc, attn2_w, bfE, w_x + H);
    } else {
        hipMemsetAsync(w_x + H, 0, H * sizeof(float), stream);
    }

    matvec_k<<<H1 / 4, 256, 0, stream>>>(prenet_w, input, prenet_b, w_h1, H1, OUTN, 1);
    matvec_k<<<H / 4, 256, 0, stream>>>(prenet2_w, w_h1, prenet2_b, w_x, H, H1, 1);
    matvec_k<<<H / 4, 256, 0, stream>>>(attn1_w, w_x, nullptr, w_way, H, H, 0);

    if (fast) {
        gamma_gemm8p<<<dim3(T / 128, H / 64), 256, 0, stream>>>(bfE, bfW2, w_way, attn3_w, w_gpart);
        gsum_k<<<T / 256, 256, 0, stream>>>(w_gpart, w_gamma);
        softmax_k<<<1, 1024, 0, stream>>>(w_gamma, attn_w, T);
    } else {
        hipMemsetAsync(w_gamma, 0, T * sizeof(float), stream);
        gamma_gemm<<<dim3(T / BM, H / BN), 256, 0, stream>>>(enc, attn2_w, w_way, attn3_w, w_gamma);
        softmax_k<<<1, 1024, 0, stream>>>(w_gamma, attn_w, T);
    }

    attn_apply_k<<<T / 32, 256, 0, stream>>>(enc, attn_w, w_x + H);
    // GRU: the proven 3-dispatch matvec_k trio (r10 = 134 total; every
    // alternative regressed: fused r11, block r12, wide r13, 2-wave r14).
    matvec_k<<<(3 * H) / 4, 256, 0, stream>>>(gru_w_ih, w_x, gru_b_ih, w_gi, 3 * H, 2 * H, 0);
    matvec_k<<<(3 * H) / 4, 256, 0, stream>>>(gru_w_hh, hidden, gru_b_hh, w_gh, 3 * H, H, 0);
    gru_combine_k<<<H / 256, 256, 0, stream>>>(w_gi, w_gh, hidden, h_new);
    matvec_k<<<OUTN / 4, 256, 0, stream>>>(lin_w, h_new, lin_b, w_logits, OUTN, H, 0);
    softmax_k<<<1, 1024, 0, stream>>>(w_logits, out, OUTN);
}

// Round 16
// 114.001 us; speedup vs baseline: 1.4263x; 1.0626x over previous
//
#include <hip/hip_runtime.h>
#include <hip/hip_bf16.h>

typedef __bf16 bf16x8 __attribute__((ext_vector_type(8)));
typedef __bf16 bf16x4 __attribute__((ext_vector_type(4)));
typedef float f32x4 __attribute__((ext_vector_type(4)));

#define H1 512
#define H 2048
#define OUTN 1024
#define T 4096

// ---------------------------------------------------------------------------
// Templated matvec: compile-time K -> full unroll -> the compiler issues
// many independent load-pairs ahead (MLP via ILP). Same lane-contiguous
// float4 coalescing as the proven matvec_k (r13's wide-stride broke that;
// this does not). Two accumulators to decouple the FMA chains.
// ---------------------------------------------------------------------------
template<int K, bool RELU>
__global__ __launch_bounds__(256) void matvec_t_k(
    const float* __restrict__ W, const float* __restrict__ x,
    const float* __restrict__ b, float* __restrict__ out)
{
    const int row = blockIdx.x * 4 + (threadIdx.x >> 6);
    const int lane = threadIdx.x & 63;
    const float* Wr = W + (size_t)row * K;
    float s0 = 0.f, s1 = 0.f;
    #pragma unroll
    for (int i = 0; i < K / 256; ++i) {
        int k = lane * 4 + i * 256;
        float4 w4 = *(const float4*)(Wr + k);
        float4 x4 = *(const float4*)(x + k);
        if (i & 1) s1 += w4.x * x4.x + w4.y * x4.y + w4.z * x4.z + w4.w * x4.w;
        else       s0 += w4.x * x4.x + w4.y * x4.y + w4.z * x4.z + w4.w * x4.w;
    }
    float s = s0 + s1;
    #pragma unroll
    for (int m = 32; m; m >>= 1) s += __shfl_xor(s, m, 64);
    if (lane == 0) {
        if (b) s += b[row];
        if (RELU) s = fmaxf(s, 0.f);
        out[row] = s;
    }
}

// ---------------------------------------------------------------------------
// Generic row-wise matvec (fallback path only).
// ---------------------------------------------------------------------------
__global__ __launch_bounds__(256) void matvec_k(
    const float* __restrict__ W, const float* __restrict__ x,
    const float* __restrict__ b, float* __restrict__ out,
    int R, int K, int relu)
{
    int row = blockIdx.x * 4 + (threadIdx.x >> 6);
    int lane = threadIdx.x & 63;
    if (row >= R) return;
    const float* Wr = W + (size_t)row * K;
    float s = 0.f;
    for (int k = lane * 4; k < K; k += 256) {
        float4 w4 = *(const float4*)(Wr + k);
        float4 x4 = *(const float4*)(x + k);
        s += w4.x * x4.x + w4.y * x4.y + w4.z * x4.z + w4.w * x4.w;
    }
    #pragma unroll
    for (int m = 32; m; m >>= 1) s += __shfl_xor(s, m, 64);
    if (lane == 0) {
        if (b) s += b[row];
        if (relu) s = fmaxf(s, 0.f);
        out[row] = s;
    }
}

// ---------------------------------------------------------------------------
// One-shot fp32 -> bf16 convert (proven r7-r15).
// E: FRAGMENT-MAJOR Efrag[r16][k32][lane][8] (MFMA A-operand lane order:
//    chunk (r16*64+k32)*64+lane holds E[r16*16+(lane&15)][k32*32+(lane>>4)*8+j]).
// attn2_w: XOR-swizzled rows (chunk cc -> slot cc^(row&7) per 64-col group).
// Block 0 additionally zeroes the attn_applied accumulator (8 KB).
// ---------------------------------------------------------------------------
__global__ __launch_bounds__(256) void cvt_frag_k(
    const float* __restrict__ E, const float* __restrict__ W2,
    __bf16* __restrict__ dst, float* __restrict__ zero_acc)
{
    if (blockIdx.x == 0) {
        #pragma unroll
        for (int j = 0; j < 8; ++j)
            zero_acc[threadIdx.x + 256 * j] = 0.f;
    }
    const int EC = T * H / 8;
    int c = blockIdx.x * 256 + threadIdx.x;
    const float* src;
    __bf16* d;
    if (c < EC) {
        int lane = c & 63;
        int k32 = (c >> 6) & 63;
        int r16 = c >> 12;
        int row = r16 * 16 + (lane & 15);
        int col = k32 * 32 + (lane >> 4) * 8;
        src = E + (size_t)row * H + col;
        d = dst + (size_t)c * 8;
    } else {
        int c2 = c - EC;
        int row = c2 >> 8;
        int kc = c2 & 255;
        src = W2 + (size_t)row * H + kc * 8;
        int grp = kc >> 3, cc = kc & 7;
        int sw = cc ^ (row & 7);
        d = dst + (size_t)T * H + (size_t)row * H + grp * 64 + sw * 8;
    }
    float4 a = *(const float4*)src;
    float4 b = *(const float4*)(src + 4);
    bf16x8 v = {(__bf16)a.x, (__bf16)a.y, (__bf16)a.z, (__bf16)a.w,
                (__bf16)b.x, (__bf16)b.y, (__bf16)b.z, (__bf16)b.w};
    *(bf16x8*)d = v;
}

// ---------------------------------------------------------------------------
// gamma GEMM v8p (proven r15; r8's champion loop + partial-write epilogue).
// 128x64 tile, 4 waves pure-m, grid 32x32 = 1024 blocks = 4/CU.
// ---------------------------------------------------------------------------
__global__ __launch_bounds__(256, 4) void gamma_gemm8p(
    const __bf16* __restrict__ Efrag,  // [T/16][64][64][8] fragment-major
    const __bf16* __restrict__ Bsw,    // [H][2048] swizzled bf16
    const float* __restrict__ way, const float* __restrict__ a3,
    float* __restrict__ gpart)         // [H/64][T]
{
    __shared__ __attribute__((aligned(16))) __bf16 Bs[64][64];   // 8 KB
    __shared__ float wayS[64], a3S[64];

    const int tb = blockIdx.x, hb = blockIdx.y;
    const int tid = threadIdx.x, lane = tid & 63, wid = tid >> 6;
    if (tid < 64) { wayS[tid] = way[hb * 64 + tid]; a3S[tid] = a3[hb * 64 + tid]; }

    const int K = 2048;
    const int rl = lane & 15;
    const int kg = (lane >> 4) * 8;
    const __bf16* Abase = Efrag + (((size_t)(tb * 8 + wid * 2) * 64) * 64 + lane) * 8;
    const __bf16* Bp = Bsw + (size_t)(hb * 64) * K;

    f32x4 acc[2][4] = {};

    for (int t = 0; t < 32; ++t) {
        const int k0 = t * 64;
        #pragma unroll
        for (int j = 0; j < 2; ++j) {
            int c = tid + j * 256;
            int row_ = c >> 3, cc_ = c & 7;
            const __bf16* s_ = Bp + (size_t)row_ * K + k0 + cc_ * 8;
            __builtin_amdgcn_global_load_lds(
                (const __attribute__((address_space(1))) void*)s_,
                (__attribute__((address_space(3))) void*)((char*)&Bs[0][0] + c * 16),
                16, 0, 0);
        }
        bf16x8 af[2][2];
        #pragma unroll
        for (int mi = 0; mi < 2; ++mi)
            #pragma unroll
            for (int kk = 0; kk < 2; ++kk)
                af[mi][kk] = *(const bf16x8*)(Abase +
                    ((size_t)(mi * 64 + t * 2 + kk) * 64) * 8);

        __syncthreads();

        #pragma unroll
        for (int kk = 0; kk < 2; ++kk) {
            bf16x8 bfm[4];
            const int kb = (kg + kk * 32) * 2;
            #pragma unroll
            for (int ni = 0; ni < 4; ++ni) {
                int r_ = ni * 16 + rl;
                bfm[ni] = *(const bf16x8*)((const char*)&Bs[0][0] + r_ * 128 + (kb ^ ((r_ & 7) << 4)));
            }
            #pragma unroll
            for (int mi = 0; mi < 2; ++mi)
                #pragma unroll
                for (int ni = 0; ni < 4; ++ni)
                    acc[mi][ni] = __builtin_amdgcn_mfma_f32_16x16x32_bf16(
                        af[mi][kk], bfm[ni], acc[mi][ni], 0, 0, 0);
        }
        __syncthreads();
    }

    // Epilogue: tanh + weighted reduce over h, clean partial write.
    const int rg = lane >> 4;
    #pragma unroll
    for (int mi = 0; mi < 2; ++mi) {
        float sr[4] = {0.f, 0.f, 0.f, 0.f};
        #pragma unroll
        for (int ni = 0; ni < 4; ++ni) {
            int h = ni * 16 + rl;
            float wh = wayS[h];
            float ah = a3S[h];
            #pragma unroll
            for (int r = 0; r < 4; ++r)
                sr[r] += tanhf(wh + acc[mi][ni][r]) * ah;
        }
        #pragma unroll
        for (int m = 1; m < 16; m <<= 1) {
            #pragma unroll
            for (int r = 0; r < 4; ++r)
                sr[r] += __shfl_xor(sr[r], m, 64);
        }
        if (rl == 0) {
            int t_ = tb * 128 + wid * 32 + mi * 16 + rg * 4;
            #pragma unroll
            for (int r = 0; r < 4; ++r)
                gpart[hb * T + t_ + r] = sr[r];
        }
    }
}

// ---------------------------------------------------------------------------
// PARALLEL gpart reduction (proven r15): gamma[t] = sum_hb gpart[hb][t].
// ---------------------------------------------------------------------------
__global__ __launch_bounds__(256) void gsum_k(
    const float* __restrict__ gpart, float* __restrict__ gamma)
{
    int t = blockIdx.x * 256 + threadIdx.x;
    float s0 = 0.f, s1 = 0.f, s2 = 0.f, s3 = 0.f;
    #pragma unroll
    for (int hb = 0; hb < 32; hb += 4) {
        s0 += gpart[(hb + 0) * T + t];
        s1 += gpart[(hb + 1) * T + t];
        s2 += gpart[(hb + 2) * T + t];
        s3 += gpart[(hb + 3) * T + t];
    }
    gamma[t] = (s0 + s1) + (s2 + s3);
}

// ---------------------------------------------------------------------------
// Single-block softmax (proven): n <= 4096.
// ---------------------------------------------------------------------------
__global__ __launch_bounds__(1024) void softmax_k(
    const float* __restrict__ in, float* __restrict__ out, int n)
{
    __shared__ float sred[16];
    __shared__ float sbc;
    int tid = threadIdx.x;

    float m = -3.4e38f;
    for (int i = tid; i < n; i += 1024) m = fmaxf(m, in[i]);
    #pragma unroll
    for (int s = 32; s; s >>= 1) m = fmaxf(m, __shfl_xor(m, s, 64));
    if ((tid & 63) == 0) sred[tid >> 6] = m;
    __syncthreads();
    if (tid == 0) {
        float mm = sred[0];
        for (int i = 1; i < 16; ++i) mm = fmaxf(mm, sred[i]);
        sbc = mm;
    }
    __syncthreads();
    float mx = sbc;

    float s = 0.f;
    for (int i = tid; i < n; i += 1024) s += expf(in[i] - mx);
    #pragma unroll
    for (int sh = 32; sh; sh >>= 1) s += __shfl_xor(s, sh, 64);
    if ((tid & 63) == 0) sred[tid >> 6] = s;
    __syncthreads();
    if (tid == 0) {
        float ss = 0.f;
        for (int i = 0; i < 16; ++i) ss += sred[i];
        sbc = ss;
    }
    __syncthreads();
    float inv = 1.f / sbc;
    for (int i = tid; i < n; i += 1024) out[i] = expf(in[i] - mx) * inv;
}

// ---------------------------------------------------------------------------
// attn_applied from the FRAGMENT-MAJOR bf16 E copy (halves traffic vs fp32).
// Read in native fragment order: consecutive lanes -> consecutive 16B chunks
// (perfectly coalesced 1KB/wave -- unlike r3's swizzle-scatter version).
// Wave w of block covers k32 = bx*4+w (32 h's); 8 r16-groups over blockIdx.y
// for wave-count/MLP; 16-lane shfl combine; 4 atomicAdds per wave.
// ---------------------------------------------------------------------------
__global__ __launch_bounds__(256) void attn_apply_frag_k(
    const __bf16* __restrict__ Efrag, const float* __restrict__ w,
    float* __restrict__ outacc)
{
    const int wid = threadIdx.x >> 6, lane = threadIdx.x & 63;
    const int k32 = blockIdx.x * 4 + wid;      // 0..63
    const int r16b = blockIdx.y * 32;          // 8 groups of 32
    const int tlow = lane & 15;
    float a[8] = {0.f, 0.f, 0.f, 0.f, 0.f, 0.f, 0.f, 0.f};
    for (int r16 = r16b; r16 < r16b + 32; ++r16) {
        bf16x8 v = *(const bf16x8*)(Efrag + (((size_t)r16 * 64 + k32) * 64 + lane) * 8);
        float wt = w[r16 * 16 + tlow];
        #pragma unroll
        for (int j = 0; j < 8; ++j)
            a[j] += wt * (float)v[j];
    }
    #pragma unroll
    for (int m = 1; m < 16; m <<= 1) {
        #pragma unroll
        for (int j = 0; j < 8; ++j)
            a[j] += __shfl_xor(a[j], m, 64);
    }
    if (tlow == 0) {
        int h = k32 * 32 + (lane >> 4) * 8;
        #pragma unroll
        for (int j = 0; j < 8; ++j)
            atomicAdd(&outacc[h + j], a[j]);
    }
}

// fp32 fallback attn_apply
__global__ __launch_bounds__(256) void attn_apply_k(
    const float* __restrict__ E, const float* __restrict__ w,
    float* __restrict__ outacc)
{
    int tid = threadIdx.x;
    int t0 = blockIdx.x * 32;
    float a[8] = {0.f, 0.f, 0.f, 0.f, 0.f, 0.f, 0.f, 0.f};
    for (int t = t0; t < t0 + 32; ++t) {
        float wt = w[t];
        const float* Er = E + (size_t)t * H;
        #pragma unroll
        for (int j = 0; j < 8; ++j)
            a[j] += wt * Er[tid + 256 * j];
    }
    #pragma unroll
    for (int j = 0; j < 8; ++j)
        atomicAdd(&outacc[tid + 256 * j], a[j]);
}

// ---------------------------------------------------------------------------
// GRU gate combine (proven): h_new = (1-z)*n + z*h0
// ---------------------------------------------------------------------------
__global__ __launch_bounds__(256) void gru_combine_k(
    const float* __restrict__ gi, const float* __restrict__ gh,
    const float* __restrict__ h0, float* __restrict__ hout)
{
    int h = blockIdx.x * 256 + threadIdx.x;
    float ir = gi[h], iz = gi[H + h], in_ = gi[2 * H + h];
    float hr = gh[h], hz = gh[H + h], hn = gh[2 * H + h];
    float r = 1.f / (1.f + expf(-(ir + hr)));
    float z = 1.f / (1.f + expf(-(iz + hz)));
    float n = tanhf(in_ + r * hn);
    hout[h] = (1.f - z) * n + z * h0[h];
}

// ---------------------------------------------------------------------------
// Fallback fp32-staged gamma GEMM (used only if ws too small).
// ---------------------------------------------------------------------------
#define BM 128
#define BN 128
#define BK 32
#define LSTR 40

__global__ __launch_bounds__(256) void gamma_gemm(
    const float* __restrict__ E, const float* __restrict__ W2,
    const float* __restrict__ way, const float* __restrict__ a3,
    float* __restrict__ gamma)
{
    __shared__ __bf16 As[BM][LSTR];
    __shared__ __bf16 Bs[BN][LSTR];
    __shared__ float wayS[BN];
    __shared__ float a3S[BN];

    const int tb = blockIdx.x, hb = blockIdx.y;
    const int tid = threadIdx.x, lane = tid & 63, wid = tid >> 6;
    const int wr = wid >> 1, wc = wid & 1;
    if (tid < BN) { wayS[tid] = way[hb * BN + tid]; a3S[tid] = a3[hb * BN + tid]; }

    f32x4 acc[4][4] = {};
    const int K = 2048;
    const float* Ep  = E  + (size_t)(tb * BM) * K;
    const float* W2p = W2 + (size_t)(hb * BN) * K;
    const int rl = lane & 15;
    const int kg = (lane >> 4) * 8;

    for (int k0 = 0; k0 < K; k0 += BK) {
        __syncthreads();
        #pragma unroll
        for (int i = 0; i < 4; ++i) {
            int c = tid + i * 256;
            int row = c >> 3;
            int col = (c & 7) * 4;
            float4 va = *(const float4*)(Ep + (size_t)row * K + k0 + col);
            bf16x4 pa = {(__bf16)va.x, (__bf16)va.y, (__bf16)va.z, (__bf16)va.w};
            *(bf16x4*)&As[row][col] = pa;
            float4 vb = *(const float4*)(W2p + (size_t)row * K + k0 + col);
            bf16x4 pb = {(__bf16)vb.x, (__bf16)vb.y, (__bf16)vb.z, (__bf16)vb.w};
            *(bf16x4*)&Bs[row][col] = pb;
        }
        __syncthreads();
        bf16x8 af[4], bfr[4];
        #pragma unroll
        for (int mi = 0; mi < 4; ++mi)
            af[mi] = *(const bf16x8*)&As[wr * 64 + mi * 16 + rl][kg];
        #pragma unroll
        for (int ni = 0; ni < 4; ++ni)
            bfr[ni] = *(const bf16x8*)&Bs[wc * 64 + ni * 16 + rl][kg];
        #pragma unroll
        for (int mi = 0; mi < 4; ++mi)
            #pragma unroll
            for (int ni = 0; ni < 4; ++ni)
                acc[mi][ni] = __builtin_amdgcn_mfma_f32_16x16x32_bf16(
                    af[mi], bfr[ni], acc[mi][ni], 0, 0, 0);
    }

    const int rg = lane >> 4;
    #pragma unroll
    for (int mi = 0; mi < 4; ++mi) {
        float sr[4] = {0.f, 0.f, 0.f, 0.f};
        #pragma unroll
        for (int ni = 0; ni < 4; ++ni) {
            int h = wc * 64 + ni * 16 + rl;
            float wh = wayS[h];
            float ah = a3S[h];
            #pragma unroll
            for (int r = 0; r < 4; ++r)
                sr[r] += tanhf(wh + acc[mi][ni][r]) * ah;
        }
        #pragma unroll
        for (int m = 1; m < 16; m <<= 1) {
            #pragma unroll
            for (int r = 0; r < 4; ++r)
                sr[r] += __shfl_xor(sr[r], m, 64);
        }
        if (rl == 0) {
            int t = tb * BM + wr * 64 + mi * 16 + rg * 4;
            #pragma unroll
            for (int r = 0; r < 4; ++r)
                atomicAdd(&gamma[t + r], sr[r]);
        }
    }
}

// ---------------------------------------------------------------------------
extern "C" void kernel_launch(void* const* d_in, const int* in_sizes, int n_in,
                              void* d_out, int out_size, void* d_ws, size_t ws_size,
                              hipStream_t stream)
{
    const float* input    = (const float*)d_in[0];
    const float* hidden   = (const float*)d_in[1];
    const float* enc      = (const float*)d_in[2];
    const float* prenet_w = (const float*)d_in[3];
    const float* prenet_b = (const float*)d_in[4];
    const float* prenet2_w= (const float*)d_in[5];
    const float* prenet2_b= (const float*)d_in[6];
    const float* attn1_w  = (const float*)d_in[7];
    const float* attn2_w  = (const float*)d_in[8];
    const float* attn3_w  = (const float*)d_in[9];
    const float* gru_w_ih = (const float*)d_in[10];
    const float* gru_w_hh = (const float*)d_in[11];
    const float* gru_b_ih = (const float*)d_in[12];
    const float* gru_b_hh = (const float*)d_in[13];
    const float* lin_w    = (const float*)d_in[14];
    const float* lin_b    = (const float*)d_in[15];

    float* out = (float*)d_out;
    float* h_new = out + OUTN;
    float* attn_w = out + OUTN + H;

    float* ws = (float*)d_ws;
    float* w_h1     = ws;                 // 512
    float* w_way    = w_h1 + 512;         // 2048
    float* w_x      = w_way + H;          // 4096 (em6 ++ attn_applied)
    float* w_logits = w_x + 2 * H;        // 1024
    float* w_gamma  = w_logits + OUTN;    // 4096
    float* w_gi     = w_gamma + T;        // 6144
    float* w_gh     = w_gi + 3 * H;       // 6144
    float* w_gpart  = w_gh + 3 * H;       // 32*4096 = 131072

    const size_t BF_OFF = 1 << 20;
    const size_t BF_BYTES = (size_t)(T + H) * H * sizeof(__bf16);   // 24 MB
    bool fast = (ws_size >= BF_OFF + BF_BYTES);
    __bf16* bfE  = (__bf16*)((char*)d_ws + BF_OFF);   // fragment-major Efrag
    __bf16* bfW2 = bfE + (size_t)T * H;               // swizzled W2

    if (fast) {
        // also zeroes w_x+H (attn_applied accumulator) in block 0
        cvt_frag_k<<<(T + H) * (H / 8) / 256, 256, 0, stream>>>(enc, attn2_w, bfE, w_x + H);
    } else {
        hipMemsetAsync(w_x + H, 0, H * sizeof(float), stream);
    }

    matvec_t_k<OUTN, true><<<H1 / 4, 256, 0, stream>>>(prenet_w, input, prenet_b, w_h1);
    matvec_t_k<H1, true><<<H / 4, 256, 0, stream>>>(prenet2_w, w_h1, prenet2_b, w_x);
    matvec_t_k<H, false><<<H / 4, 256, 0, stream>>>(attn1_w, w_x, nullptr, w_way);

    if (fast) {
        gamma_gemm8p<<<dim3(T / 128, H / 64), 256, 0, stream>>>(bfE, bfW2, w_way, attn3_w, w_gpart);
        gsum_k<<<T / 256, 256, 0, stream>>>(w_gpart, w_gamma);
        softmax_k<<<1, 1024, 0, stream>>>(w_gamma, attn_w, T);
    } else {
        hipMemsetAsync(w_gamma, 0, T * sizeof(float), stream);
        gamma_gemm<<<dim3(T / BM, H / BN), 256, 0, stream>>>(enc, attn2_w, w_way, attn3_w, w_gamma);
        softmax_k<<<1, 1024, 0, stream>>>(w_gamma, attn_w, T);
    }

    if (fast)
        attn_apply_frag_k<<<dim3(16, 8), 256, 0, stream>>>(bfE, attn_w, w_x + H);
    else
        attn_apply_k<<<T / 32, 256, 0, stream>>>(enc, attn_w, w_x + H);

    // GRU: proven 3-dispatch trio, now compile-time-K for load lookahead
    matvec_t_k<2 * H, false><<<(3 * H) / 4, 256, 0, stream>>>(gru_w_ih, w_x, gru_b_ih, w_gi);
    matvec_t_k<H, false><<<(3 * H) / 4, 256, 0, stream>>>(gru_w_hh, hidden, gru_b_hh, w_gh);
    gru_combine_k<<<H / 256, 256, 0, stream>>>(w_gi, w_gh, hidden, h_new);
    matvec_t_k<H, false><<<OUTN / 4, 256, 0, stream>>>(lin_w, h_new, lin_b, w_logits);
    softmax_k<<<1, 1024, 0, stream>>>(w_logits, out, OUTN);
}

// Round 17
// 112.357 us; speedup vs baseline: 1.4472x; 1.0146x over previous
//
#include <hip/hip_runtime.h>
#include <hip/hip_bf16.h>

typedef __bf16 bf16x8 __attribute__((ext_vector_type(8)));
typedef __bf16 bf16x4 __attribute__((ext_vector_type(4)));
typedef float f32x4 __attribute__((ext_vector_type(4)));

#define H1 512
#define H 2048
#define OUTN 1024
#define T 4096

// ---------------------------------------------------------------------------
// Templated matvec (proven r16): compile-time K -> full unroll -> MLP via
// ILP, lane-contiguous float4 coalescing, two decoupled accumulators.
// ---------------------------------------------------------------------------
template<int K, bool RELU>
__global__ __launch_bounds__(256) void matvec_t_k(
    const float* __restrict__ W, const float* __restrict__ x,
    const float* __restrict__ b, float* __restrict__ out)
{
    const int row = blockIdx.x * 4 + (threadIdx.x >> 6);
    const int lane = threadIdx.x & 63;
    const float* Wr = W + (size_t)row * K;
    float s0 = 0.f, s1 = 0.f;
    #pragma unroll
    for (int i = 0; i < K / 256; ++i) {
        int k = lane * 4 + i * 256;
        float4 w4 = *(const float4*)(Wr + k);
        float4 x4 = *(const float4*)(x + k);
        if (i & 1) s1 += w4.x * x4.x + w4.y * x4.y + w4.z * x4.z + w4.w * x4.w;
        else       s0 += w4.x * x4.x + w4.y * x4.y + w4.z * x4.z + w4.w * x4.w;
    }
    float s = s0 + s1;
    #pragma unroll
    for (int m = 32; m; m >>= 1) s += __shfl_xor(s, m, 64);
    if (lane == 0) {
        if (b) s += b[row];
        if (RELU) s = fmaxf(s, 0.f);
        out[row] = s;
    }
}

// ---------------------------------------------------------------------------
// Generic row-wise matvec (fallback path only).
// ---------------------------------------------------------------------------
__global__ __launch_bounds__(256) void matvec_k(
    const float* __restrict__ W, const float* __restrict__ x,
    const float* __restrict__ b, float* __restrict__ out,
    int R, int K, int relu)
{
    int row = blockIdx.x * 4 + (threadIdx.x >> 6);
    int lane = threadIdx.x & 63;
    if (row >= R) return;
    const float* Wr = W + (size_t)row * K;
    float s = 0.f;
    for (int k = lane * 4; k < K; k += 256) {
        float4 w4 = *(const float4*)(Wr + k);
        float4 x4 = *(const float4*)(x + k);
        s += w4.x * x4.x + w4.y * x4.y + w4.z * x4.z + w4.w * x4.w;
    }
    #pragma unroll
    for (int m = 32; m; m >>= 1) s += __shfl_xor(s, m, 64);
    if (lane == 0) {
        if (b) s += b[row];
        if (relu) s = fmaxf(s, 0.f);
        out[row] = s;
    }
}

// ---------------------------------------------------------------------------
// One-shot fp32 -> bf16 convert (proven r7-r16).
// E: FRAGMENT-MAJOR Efrag[r16][k32][lane][8] (MFMA A-operand lane order).
// attn2_w: XOR-swizzled rows (chunk cc -> slot cc^(row&7) per 64-col group).
// Block 0 additionally zeroes the attn_applied accumulator (8 KB).
// ---------------------------------------------------------------------------
__global__ __launch_bounds__(256) void cvt_frag_k(
    const float* __restrict__ E, const float* __restrict__ W2,
    __bf16* __restrict__ dst, float* __restrict__ zero_acc)
{
    if (blockIdx.x == 0) {
        #pragma unroll
        for (int j = 0; j < 8; ++j)
            zero_acc[threadIdx.x + 256 * j] = 0.f;
    }
    const int EC = T * H / 8;
    int c = blockIdx.x * 256 + threadIdx.x;
    const float* src;
    __bf16* d;
    if (c < EC) {
        int lane = c & 63;
        int k32 = (c >> 6) & 63;
        int r16 = c >> 12;
        int row = r16 * 16 + (lane & 15);
        int col = k32 * 32 + (lane >> 4) * 8;
        src = E + (size_t)row * H + col;
        d = dst + (size_t)c * 8;
    } else {
        int c2 = c - EC;
        int row = c2 >> 8;
        int kc = c2 & 255;
        src = W2 + (size_t)row * H + kc * 8;
        int grp = kc >> 3, cc = kc & 7;
        int sw = cc ^ (row & 7);
        d = dst + (size_t)T * H + (size_t)row * H + grp * 64 + sw * 8;
    }
    float4 a = *(const float4*)src;
    float4 b = *(const float4*)(src + 4);
    bf16x8 v = {(__bf16)a.x, (__bf16)a.y, (__bf16)a.z, (__bf16)a.w,
                (__bf16)b.x, (__bf16)b.y, (__bf16)b.z, (__bf16)b.w};
    *(bf16x8*)d = v;
}

// ---------------------------------------------------------------------------
// gamma GEMM v9w: 128x128 tile, 8 waves (2 col-halves x 4 row-groups),
// grid (32,16) = 512 blocks = 2/CU x 8 waves = 16 waves/CU (same TLP as the
// proven r8 config) but HALF the barriers-per-MFMA and HALF the B traffic.
// A: coalesced fragment-major global->VGPR (r8's proven path). B: single-
// buffered swizzled LDS [128][64] (16 KB) via global_load_lds w16,
// conflict-free swizzled ds_read_b128. BK=64. Partial-write epilogue.
// ---------------------------------------------------------------------------
__global__ __launch_bounds__(512, 2) void gamma_gemm9w(
    const __bf16* __restrict__ Efrag,  // [T/16][64][64][8] fragment-major
    const __bf16* __restrict__ Bsw,    // [H][2048] swizzled bf16
    const float* __restrict__ way, const float* __restrict__ a3,
    float* __restrict__ gpart)         // [H/64][T]
{
    __shared__ __attribute__((aligned(16))) __bf16 Bs[128][64];  // 16 KB
    __shared__ float wayS[128], a3S[128];

    const int tb = blockIdx.x, hb = blockIdx.y;
    const int tid = threadIdx.x, lane = tid & 63, wid = tid >> 6;
    const int wr = wid & 3;        // row group: rows tb*128 + wr*32 ..
    const int wc = wid >> 2;       // col half: cols hb*128 + wc*64 ..
    if (tid < 128) { wayS[tid] = way[hb * 128 + tid]; a3S[tid] = a3[hb * 128 + tid]; }

    const int K = 2048;
    const int rl = lane & 15;
    const int kg = (lane >> 4) * 8;
    const __bf16* Abase = Efrag + (((size_t)(tb * 8 + wr * 2) * 64) * 64 + lane) * 8;
    const __bf16* Bp = Bsw + (size_t)(hb * 128) * K;

    f32x4 acc[2][4] = {};

    for (int t = 0; t < 32; ++t) {
        const int k0 = t * 64;
        // stage B: 128 rows x 64 cols = 1024 x 16B chunks, 2 per thread
        #pragma unroll
        for (int j = 0; j < 2; ++j) {
            int c = tid + j * 512;
            int row_ = c >> 3, cc_ = c & 7;
            const __bf16* s_ = Bp + (size_t)row_ * K + k0 + cc_ * 8;
            __builtin_amdgcn_global_load_lds(
                (const __attribute__((address_space(1))) void*)s_,
                (__attribute__((address_space(3))) void*)((char*)&Bs[0][0] + c * 16),
                16, 0, 0);
        }
        // A fragments: 4 coalesced b128 loads (fragment-major layout)
        bf16x8 af[2][2];
        #pragma unroll
        for (int mi = 0; mi < 2; ++mi)
            #pragma unroll
            for (int kk = 0; kk < 2; ++kk)
                af[mi][kk] = *(const bf16x8*)(Abase +
                    ((size_t)(mi * 64 + t * 2 + kk) * 64) * 8);

        __syncthreads();   // drains vmcnt: B in LDS, A in regs; barrier

        #pragma unroll
        for (int kk = 0; kk < 2; ++kk) {
            bf16x8 bfm[4];
            const int kb = (kg + kk * 32) * 2;
            #pragma unroll
            for (int ni = 0; ni < 4; ++ni) {
                int r_ = wc * 64 + ni * 16 + rl;
                bfm[ni] = *(const bf16x8*)((const char*)&Bs[0][0] + r_ * 128 + (kb ^ ((r_ & 7) << 4)));
            }
            #pragma unroll
            for (int mi = 0; mi < 2; ++mi)
                #pragma unroll
                for (int ni = 0; ni < 4; ++ni)
                    acc[mi][ni] = __builtin_amdgcn_mfma_f32_16x16x32_bf16(
                        af[mi][kk], bfm[ni], acc[mi][ni], 0, 0, 0);
        }
        __syncthreads();   // all waves done reading Bs before next overwrite
    }

    // Epilogue: tanh + weighted reduce over h, clean partial write.
    // D layout: col = lane&15 (h), row = (lane>>4)*4 + r (t)
    const int rg = lane >> 4;
    #pragma unroll
    for (int mi = 0; mi < 2; ++mi) {
        float sr[4] = {0.f, 0.f, 0.f, 0.f};
        #pragma unroll
        for (int ni = 0; ni < 4; ++ni) {
            int h = wc * 64 + ni * 16 + rl;
            float wh = wayS[h];
            float ah = a3S[h];
            #pragma unroll
            for (int r = 0; r < 4; ++r)
                sr[r] += tanhf(wh + acc[mi][ni][r]) * ah;
        }
        #pragma unroll
        for (int m = 1; m < 16; m <<= 1) {
            #pragma unroll
            for (int r = 0; r < 4; ++r)
                sr[r] += __shfl_xor(sr[r], m, 64);
        }
        if (rl == 0) {
            int t_ = tb * 128 + wr * 32 + mi * 16 + rg * 4;
            int hbg = hb * 2 + wc;           // global 64-col group, 0..31
            #pragma unroll
            for (int r = 0; r < 4; ++r)
                gpart[hbg * T + t_ + r] = sr[r];
        }
    }
}

// ---------------------------------------------------------------------------
// PARALLEL gpart reduction (proven r15/r16): gamma[t] = sum_hb gpart[hb][t].
// ---------------------------------------------------------------------------
__global__ __launch_bounds__(256) void gsum_k(
    const float* __restrict__ gpart, float* __restrict__ gamma)
{
    int t = blockIdx.x * 256 + threadIdx.x;
    float s0 = 0.f, s1 = 0.f, s2 = 0.f, s3 = 0.f;
    #pragma unroll
    for (int hb = 0; hb < 32; hb += 4) {
        s0 += gpart[(hb + 0) * T + t];
        s1 += gpart[(hb + 1) * T + t];
        s2 += gpart[(hb + 2) * T + t];
        s3 += gpart[(hb + 3) * T + t];
    }
    gamma[t] = (s0 + s1) + (s2 + s3);
}

// ---------------------------------------------------------------------------
// Single-block softmax (proven): n <= 4096.
// ---------------------------------------------------------------------------
__global__ __launch_bounds__(1024) void softmax_k(
    const float* __restrict__ in, float* __restrict__ out, int n)
{
    __shared__ float sred[16];
    __shared__ float sbc;
    int tid = threadIdx.x;

    float m = -3.4e38f;
    for (int i = tid; i < n; i += 1024) m = fmaxf(m, in[i]);
    #pragma unroll
    for (int s = 32; s; s >>= 1) m = fmaxf(m, __shfl_xor(m, s, 64));
    if ((tid & 63) == 0) sred[tid >> 6] = m;
    __syncthreads();
    if (tid == 0) {
        float mm = sred[0];
        for (int i = 1; i < 16; ++i) mm = fmaxf(mm, sred[i]);
        sbc = mm;
    }
    __syncthreads();
    float mx = sbc;

    float s = 0.f;
    for (int i = tid; i < n; i += 1024) s += expf(in[i] - mx);
    #pragma unroll
    for (int sh = 32; sh; sh >>= 1) s += __shfl_xor(s, sh, 64);
    if ((tid & 63) == 0) sred[tid >> 6] = s;
    __syncthreads();
    if (tid == 0) {
        float ss = 0.f;
        for (int i = 0; i < 16; ++i) ss += sred[i];
        sbc = ss;
    }
    __syncthreads();
    float inv = 1.f / sbc;
    for (int i = tid; i < n; i += 1024) out[i] = expf(in[i] - mx) * inv;
}

// ---------------------------------------------------------------------------
// attn_applied from the FRAGMENT-MAJOR bf16 E copy (proven r16).
// ---------------------------------------------------------------------------
__global__ __launch_bounds__(256) void attn_apply_frag_k(
    const __bf16* __restrict__ Efrag, const float* __restrict__ w,
    float* __restrict__ outacc)
{
    const int wid = threadIdx.x >> 6, lane = threadIdx.x & 63;
    const int k32 = blockIdx.x * 4 + wid;      // 0..63
    const int r16b = blockIdx.y * 32;          // 8 groups of 32
    const int tlow = lane & 15;
    float a[8] = {0.f, 0.f, 0.f, 0.f, 0.f, 0.f, 0.f, 0.f};
    for (int r16 = r16b; r16 < r16b + 32; ++r16) {
        bf16x8 v = *(const bf16x8*)(Efrag + (((size_t)r16 * 64 + k32) * 64 + lane) * 8);
        float wt = w[r16 * 16 + tlow];
        #pragma unroll
        for (int j = 0; j < 8; ++j)
            a[j] += wt * (float)v[j];
    }
    #pragma unroll
    for (int m = 1; m < 16; m <<= 1) {
        #pragma unroll
        for (int j = 0; j < 8; ++j)
            a[j] += __shfl_xor(a[j], m, 64);
    }
    if (tlow == 0) {
        int h = k32 * 32 + (lane >> 4) * 8;
        #pragma unroll
        for (int j = 0; j < 8; ++j)
            atomicAdd(&outacc[h + j], a[j]);
    }
}

// fp32 fallback attn_apply
__global__ __launch_bounds__(256) void attn_apply_k(
    const float* __restrict__ E, const float* __restrict__ w,
    float* __restrict__ outacc)
{
    int tid = threadIdx.x;
    int t0 = blockIdx.x * 32;
    float a[8] = {0.f, 0.f, 0.f, 0.f, 0.f, 0.f, 0.f, 0.f};
    for (int t = t0; t < t0 + 32; ++t) {
        float wt = w[t];
        const float* Er = E + (size_t)t * H;
        #pragma unroll
        for (int j = 0; j < 8; ++j)
            a[j] += wt * Er[tid + 256 * j];
    }
    #pragma unroll
    for (int j = 0; j < 8; ++j)
        atomicAdd(&outacc[tid + 256 * j], a[j]);
}

// ---------------------------------------------------------------------------
// GRU gate combine (proven): h_new = (1-z)*n + z*h0
// ---------------------------------------------------------------------------
__global__ __launch_bounds__(256) void gru_combine_k(
    const float* __restrict__ gi, const float* __restrict__ gh,
    const float* __restrict__ h0, float* __restrict__ hout)
{
    int h = blockIdx.x * 256 + threadIdx.x;
    float ir = gi[h], iz = gi[H + h], in_ = gi[2 * H + h];
    float hr = gh[h], hz = gh[H + h], hn = gh[2 * H + h];
    float r = 1.f / (1.f + expf(-(ir + hr)));
    float z = 1.f / (1.f + expf(-(iz + hz)));
    float n = tanhf(in_ + r * hn);
    hout[h] = (1.f - z) * n + z * h0[h];
}

// ---------------------------------------------------------------------------
// Fallback fp32-staged gamma GEMM (used only if ws too small).
// ---------------------------------------------------------------------------
#define BM 128
#define BN 128
#define BK 32
#define LSTR 40

__global__ __launch_bounds__(256) void gamma_gemm(
    const float* __restrict__ E, const float* __restrict__ W2,
    const float* __restrict__ way, const float* __restrict__ a3,
    float* __restrict__ gamma)
{
    __shared__ __bf16 As[BM][LSTR];
    __shared__ __bf16 Bs[BN][LSTR];
    __shared__ float wayS[BN];
    __shared__ float a3S[BN];

    const int tb = blockIdx.x, hb = blockIdx.y;
    const int tid = threadIdx.x, lane = tid & 63, wid = tid >> 6;
    const int wr = wid >> 1, wc = wid & 1;
    if (tid < BN) { wayS[tid] = way[hb * BN + tid]; a3S[tid] = a3[hb * BN + tid]; }

    f32x4 acc[4][4] = {};
    const int K = 2048;
    const float* Ep  = E  + (size_t)(tb * BM) * K;
    const float* W2p = W2 + (size_t)(hb * BN) * K;
    const int rl = lane & 15;
    const int kg = (lane >> 4) * 8;

    for (int k0 = 0; k0 < K; k0 += BK) {
        __syncthreads();
        #pragma unroll
        for (int i = 0; i < 4; ++i) {
            int c = tid + i * 256;
            int row = c >> 3;
            int col = (c & 7) * 4;
            float4 va = *(const float4*)(Ep + (size_t)row * K + k0 + col);
            bf16x4 pa = {(__bf16)va.x, (__bf16)va.y, (__bf16)va.z, (__bf16)va.w};
            *(bf16x4*)&As[row][col] = pa;
            float4 vb = *(const float4*)(W2p + (size_t)row * K + k0 + col);
            bf16x4 pb = {(__bf16)vb.x, (__bf16)vb.y, (__bf16)vb.z, (__bf16)vb.w};
            *(bf16x4*)&Bs[row][col] = pb;
        }
        __syncthreads();
        bf16x8 af[4], bfr[4];
        #pragma unroll
        for (int mi = 0; mi < 4; ++mi)
            af[mi] = *(const bf16x8*)&As[wr * 64 + mi * 16 + rl][kg];
        #pragma unroll
        for (int ni = 0; ni < 4; ++ni)
            bfr[ni] = *(const bf16x8*)&Bs[wc * 64 + ni * 16 + rl][kg];
        #pragma unroll
        for (int mi = 0; mi < 4; ++mi)
            #pragma unroll
            for (int ni = 0; ni < 4; ++ni)
                acc[mi][ni] = __builtin_amdgcn_mfma_f32_16x16x32_bf16(
                    af[mi], bfr[ni], acc[mi][ni], 0, 0, 0);
    }

    const int rg = lane >> 4;
    #pragma unroll
    for (int mi = 0; mi < 4; ++mi) {
        float sr[4] = {0.f, 0.f, 0.f, 0.f};
        #pragma unroll
        for (int ni = 0; ni < 4; ++ni) {
            int h = wc * 64 + ni * 16 + rl;
            float wh = wayS[h];
            float ah = a3S[h];
            #pragma unroll
            for (int r = 0; r < 4; ++r)
                sr[r] += tanhf(wh + acc[mi][ni][r]) * ah;
        }
        #pragma unroll
        for (int m = 1; m < 16; m <<= 1) {
            #pragma unroll
            for (int r = 0; r < 4; ++r)
                sr[r] += __shfl_xor(sr[r], m, 64);
        }
        if (rl == 0) {
            int t = tb * BM + wr * 64 + mi * 16 + rg * 4;
            #pragma unroll
            for (int r = 0; r < 4; ++r)
                atomicAdd(&gamma[t + r], sr[r]);
        }
    }
}

// ---------------------------------------------------------------------------
extern "C" void kernel_launch(void* const* d_in, const int* in_sizes, int n_in,
                              void* d_out, int out_size, void* d_ws, size_t ws_size,
                              hipStream_t stream)
{
    const float* input    = (const float*)d_in[0];
    const float* hidden   = (const float*)d_in[1];
    const float* enc      = (const float*)d_in[2];
    const float* prenet_w = (const float*)d_in[3];
    const float* prenet_b = (const float*)d_in[4];
    const float* prenet2_w= (const float*)d_in[5];
    const float* prenet2_b= (const float*)d_in[6];
    const float* attn1_w  = (const float*)d_in[7];
    const float* attn2_w  = (const float*)d_in[8];
    const float* attn3_w  = (const float*)d_in[9];
    const float* gru_w_ih = (const float*)d_in[10];
    const float* gru_w_hh = (const float*)d_in[11];
    const float* gru_b_ih = (const float*)d_in[12];
    const float* gru_b_hh = (const float*)d_in[13];
    const float* lin_w    = (const float*)d_in[14];
    const float* lin_b    = (const float*)d_in[15];

    float* out = (float*)d_out;
    float* h_new = out + OUTN;
    float* attn_w = out + OUTN + H;

    float* ws = (float*)d_ws;
    float* w_h1     = ws;                 // 512
    float* w_way    = w_h1 + 512;         // 2048
    float* w_x      = w_way + H;          // 4096 (em6 ++ attn_applied)
    float* w_logits = w_x + 2 * H;        // 1024
    float* w_gamma  = w_logits + OUTN;    // 4096
    float* w_gi     = w_gamma + T;        // 6144
    float* w_gh     = w_gi + 3 * H;       // 6144
    float* w_gpart  = w_gh + 3 * H;       // 32*4096 = 131072

    const size_t BF_OFF = 1 << 20;
    const size_t BF_BYTES = (size_t)(T + H) * H * sizeof(__bf16);   // 24 MB
    bool fast = (ws_size >= BF_OFF + BF_BYTES);
    __bf16* bfE  = (__bf16*)((char*)d_ws + BF_OFF);   // fragment-major Efrag
    __bf16* bfW2 = bfE + (size_t)T * H;               // swizzled W2

    if (fast) {
        // also zeroes w_x+H (attn_applied accumulator) in block 0
        cvt_frag_k<<<(T + H) * (H / 8) / 256, 256, 0, stream>>>(enc, attn2_w, bfE, w_x + H);
    } else {
        hipMemsetAsync(w_x + H, 0, H * sizeof(float), stream);
    }

    matvec_t_k<OUTN, true><<<H1 / 4, 256, 0, stream>>>(prenet_w, input, prenet_b, w_h1);
    matvec_t_k<H1, true><<<H / 4, 256, 0, stream>>>(prenet2_w, w_h1, prenet2_b, w_x);
    matvec_t_k<H, false><<<H / 4, 256, 0, stream>>>(attn1_w, w_x, nullptr, w_way);

    if (fast) {
        gamma_gemm9w<<<dim3(T / 128, H / 128), 512, 0, stream>>>(bfE, bfW2, w_way, attn3_w, w_gpart);
        gsum_k<<<T / 256, 256, 0, stream>>>(w_gpart, w_gamma);
        softmax_k<<<1, 1024, 0, stream>>>(w_gamma, attn_w, T);
    } else {
        hipMemsetAsync(w_gamma, 0, T * sizeof(float), stream);
        gamma_gemm<<<dim3(T / BM, H / BN), 256, 0, stream>>>(enc, attn2_w, w_way, attn3_w, w_gamma);
        softmax_k<<<1, 1024, 0, stream>>>(w_gamma, attn_w, T);
    }

    if (fast)
        attn_apply_frag_k<<<dim3(16, 8), 256, 0, stream>>>(bfE, attn_w, w_x + H);
    else
        attn_apply_k<<<T / 32, 256, 0, stream>>>(enc, attn_w, w_x + H);

    // GRU: proven 3-dispatch trio, compile-time-K for load lookahead
    matvec_t_k<2 * H, false><<<(3 * H) / 4, 256, 0, stream>>>(gru_w_ih, w_x, gru_b_ih, w_gi);
    matvec_t_k<H, false><<<(3 * H) / 4, 256, 0, stream>>>(gru_w_hh, hidden, gru_b_hh, w_gh);
    gru_combine_k<<<H / 256, 256, 0, stream>>>(w_gi, w_gh, hidden, h_new);
    matvec_t_k<H, false><<<OUTN / 4, 256, 0, stream>>>(lin_w, h_new, lin_b, w_logits);
    softmax_k<<<1, 1024, 0, stream>>>(w_logits, out, OUTN);
}